// Round 10
// baseline (415.962 us; speedup 1.0000x reference)
//
#include <hip/hip_runtime.h>

// ---------- problem constants ----------
#define B_   4
#define L_   2048
#define H_   1024
#define KD   768
#define VD   1536
#define NHh  12
#define DKh  64
#define DVh  128
#define M_   (B_ * L_)   // 8192 rows
#define NC   32          // chunks per sequence (L/64)
#define NCID (B_ * NHh * NC)  // 1536

using bf16x8 = __attribute__((ext_vector_type(8))) __bf16;
using f32x4  = __attribute__((ext_vector_type(4))) float;
using ui4    = __attribute__((ext_vector_type(4))) unsigned int;
using f4v    = __attribute__((ext_vector_type(4))) float;
using u16x4  = __attribute__((ext_vector_type(4))) unsigned short;
using u16x8  = __attribute__((ext_vector_type(8))) unsigned short;

__device__ __forceinline__ float bf2f(unsigned short u) {
  unsigned int x = ((unsigned int)u) << 16;
  return __builtin_bit_cast(float, x);
}
__device__ __forceinline__ unsigned short f2bf(float f) {
  unsigned int u = __builtin_bit_cast(unsigned int, f);
  u += 0x7fffu + ((u >> 16) & 1u);
  return (unsigned short)(u >> 16);
}
__device__ __forceinline__ float sigmoidf_(float x) { return 1.f / (1.f + __expf(-x)); }

// async global->LDS DMA, 16B per lane; lds dest must be wave-uniform base (+lane*16 implicit)
__device__ __forceinline__ void async_copy16(const unsigned short* __restrict__ g,
                                             unsigned short* l) {
  __builtin_amdgcn_global_load_lds((const __attribute__((address_space(1))) unsigned int*)g,
                                   (__attribute__((address_space(3))) unsigned int*)l, 16, 0, 0);
}

// ---------- dtype detector: flag=1 if inputs are fp32, 0 if bf16 ----------
__global__ void detect_dtype(const unsigned short* __restrict__ hs, int* __restrict__ flag) {
  int tid = threadIdx.x;  // 256 threads
  int cnt = 0;
  for (int i = tid; i < 1024; i += 256) {
    int e = (hs[i] >> 7) & 0xFF;
    if (e >= 134) cnt++;
  }
  #pragma unroll
  for (int off = 32; off; off >>= 1) cnt += __shfl_xor(cnt, off);
  __shared__ int red[4];
  if ((tid & 63) == 0) red[tid >> 6] = cnt;
  __syncthreads();
  if (tid == 0) *flag = (red[0] + red[1] + red[2] + red[3] > 100) ? 1 : 0;
}

// ---------- convert 7 small arrays -> canonical fp32 ----------
// conv weights (a=0,1,2) are additionally TRANSPOSED: in [C][4] -> out [4][C]
__global__ void convert_small(const void* s0, const void* s1, const void* s2,
                              const void* s3, const void* s4, const void* s5, const void* s6,
                              float* d0, float* d1, float* d2, float* d3, float* d4,
                              float* d5, float* d6, const int* __restrict__ flag) {
  const int sizes[7] = {KD * 4, KD * 4, VD * 4, NHh, NHh, NHh, DVh};
  int a = blockIdx.y;
  const void* s; float* d;
  switch (a) {
    case 0: s = s0; d = d0; break;  case 1: s = s1; d = d1; break;
    case 2: s = s2; d = d2; break;  case 3: s = s3; d = d3; break;
    case 4: s = s4; d = d4; break;  case 5: s = s5; d = d5; break;
    default: s = s6; d = d6; break;
  }
  int i = blockIdx.x * 256 + threadIdx.x;
  if (i >= sizes[a]) return;
  float v = (*flag) ? ((const float*)s)[i] : bf2f(((const unsigned short*)s)[i]);
  if (a < 3) {
    int C = (a == 2) ? VD : KD;
    d[(i & 3) * C + (i >> 2)] = v;   // transposed [j][c]
  } else {
    d[i] = v;
  }
}

// ---------- ALL weight transposes + hs canonicalization in ONE launch ----------
// blocks [0,6208): 32x32 transpose tiles:
//   Wq 768 | Wk 768 | Wv 1536 | Wg 1536 | Wgk 32 | Wb 32 | Wo 1536
// blocks [6208,14400): hidden_states convert/copy (4 elems x 256 thr each)
__global__ void transpose_all(
    const void* s0, const void* s1, const void* s2, const void* s3,
    const void* s4, const void* s5, const void* s6,
    unsigned short* d0, unsigned short* d1, unsigned short* d2, unsigned short* d3,
    unsigned short* d4, unsigned short* d5, unsigned short* d6,
    const void* __restrict__ hs, unsigned short* __restrict__ c_hs,
    const int* __restrict__ flag) {
  int t = blockIdx.x;
  if (t >= 6208) {
    size_t i = ((size_t)(t - 6208) * 256 + threadIdx.x) * 4;
    if (*flag) {
      f4v v = *(const f4v*)((const float*)hs + i);
      u16x4 o;
      o.x = f2bf(v[0]); o.y = f2bf(v[1]); o.z = f2bf(v[2]); o.w = f2bf(v[3]);
      *(u16x4*)(c_hs + i) = o;
    } else {
      *(u16x4*)(c_hs + i) = *(const u16x4*)((const unsigned short*)hs + i);
    }
    return;
  }
  __shared__ unsigned short tile[32][33];
  const void* in; unsigned short* out; int R, C, ntx, tt;
  if (t < 768)       { in = s0; out = d0; R = 1024; C = 768;  ntx = 24; tt = t; }
  else if (t < 1536) { in = s1; out = d1; R = 1024; C = 768;  ntx = 24; tt = t - 768; }
  else if (t < 3072) { in = s2; out = d2; R = 1024; C = 1536; ntx = 48; tt = t - 1536; }
  else if (t < 4608) { in = s3; out = d3; R = 1024; C = 1536; ntx = 48; tt = t - 3072; }
  else if (t < 4640) { in = s4; out = d4; R = 1024; C = 12;   ntx = 1;  tt = t - 4608; }
  else if (t < 4672) { in = s5; out = d5; R = 1024; C = 12;   ntx = 1;  tt = t - 4640; }
  else               { in = s6; out = d6; R = 1536; C = 1024; ntx = 32; tt = t - 4672; }
  int f = *flag;
  int bx = tt % ntx, by = tt / ntx;
  int c0 = bx * 32, r0 = by * 32;
  int tx = threadIdx.x & 31, ty = threadIdx.x >> 5;
  #pragma unroll
  for (int i = 0; i < 32; i += 8) {
    int r = r0 + ty + i, c = c0 + tx;
    unsigned short v = 0;
    if (r < R && c < C)
      v = f ? f2bf(((const float*)in)[(size_t)r * C + c])
            : ((const unsigned short*)in)[(size_t)r * C + c];
    tile[ty + i][tx] = v;
  }
  __syncthreads();
  #pragma unroll
  for (int i = 0; i < 32; i += 8) {
    int c = c0 + ty + i, r = r0 + tx;
    if (c < C && r < R) out[(size_t)c * R + r] = tile[tx][ty + i];
  }
}

// ---------- MFMA GEMM: C[M,N] = A[M,K] * B[K,N], BT = B^T [N,K] ----------
// R10: 256x128 tile, BK=32, 512 thr (8 waves 4x2, acc[4][4]), dbuf LDS 48KB ->
// 2 blocks/CU. Rationale (R9 post-mortem): the 128^2 kernel demands ~82 B/cyc/CU
// from L2/L3 (> ~68 measured ceiling) -> cache-BW bound at ~30% MfmaUtil.
// BM=256 halves B-panel re-reads: bytes/FLOP -25%. Counted vmcnt discipline
// kept (NLD=3: 2 A-chunks + 1 B-chunk per thread per K-tile). XOR swizzle
// re-derived for 4-slot rows (src slot u^(r&3), read slot lq^(ra&3)) —
// bank-quad analysis: 8 lanes per quad over min 8 passes = conflict-free.
// f32mode: 0=bf16, 1=f32, 2=flag-selected,
//          3=fused gkbeta|q|k|v|g routing over N=4736 (gk tile FIRST at y=0).
#define BMt 256
#define BNt 128
#define BKt 32

__global__ __launch_bounds__(512, 4) void gemm_bt(
    const unsigned short* __restrict__ Ag,
    const unsigned short* __restrict__ BTg,
    void* __restrict__ Cg,
    int M, int N, int K, int f32mode, const int* __restrict__ flag,
    const float* __restrict__ bbf, const float* __restrict__ A_logf,
    const float* __restrict__ dtf,
    float* __restrict__ gkb, float* __restrict__ betab) {
  __shared__ __align__(16) unsigned short As[2][BMt * BKt];   // 2 x 16KB
  __shared__ __align__(16) unsigned short Bs[2][BNt * BKt];   // 2 x 8KB
  const int tid = threadIdx.x;
  const int wave = tid >> 6, lane = tid & 63;
  const int wr = wave >> 1, wc = wave & 1;   // 4 x 2 wave grid: 64-row x 64-col per wave
  const int lrow = lane & 15, lq = lane >> 4;
  const int row0 = blockIdx.x * BMt;
  const int bcol0 = blockIdx.y * BNt;
  const bool gkregion = (f32mode == 3) && (bcol0 < BNt);
  // C routing
  unsigned short* Cb = (unsigned short*)Cg;
  int col0 = bcol0, Nst = N;
  if (f32mode == 3 && !gkregion) {
    int r3 = bcol0 - BNt;
    int region = r3 / 1536;
    Cb += (size_t)region * (size_t)M_ * 1536;
    col0 = r3 - region * 1536;
    Nst = 1536;
  }
  f32x4 acc[4][4] = {};
  // staging (per K-tile): A = 1024 16B-chunks (2/thread), B = 512 (1/thread).
  // chunk c: row r = c>>2, LDS slot u = c&3 holds global slot u^(r&3).
  auto stage = [&](int sb, int k0) {
    #pragma unroll
    for (int i = 0; i < 2; i++) {
      int c = i * 512 + tid;
      int r = c >> 2;
      int kk = ((c & 3) ^ (r & 3)) << 3;   // pre-swizzled source slot
      async_copy16(&Ag[(size_t)(row0 + r) * K + k0 + kk],
                   &As[sb][(i * 512 + wave * 64) * 8]);
    }
    {
      int c = tid;
      int r = c >> 2;
      int kk = ((c & 3) ^ (r & 3)) << 3;
      async_copy16(&BTg[(size_t)(bcol0 + r) * K + k0 + kk],
                   &Bs[sb][(wave * 64) * 8]);
    }
  };
  const int NT = K / BKt;
  stage(0, 0);
  stage(1, BKt);
  for (int t = 0; t < NT; t++) {
    // Drain only tile t's 3 loads (per-wave oldest); tile t+1's stay in flight.
    if (t + 1 < NT) asm volatile("s_waitcnt vmcnt(3)" ::: "memory");
    else            asm volatile("s_waitcnt vmcnt(0)" ::: "memory");
    __builtin_amdgcn_s_barrier();       // all waves' tile-t loads are in LDS
    const int cur = t & 1;
    {
      bf16x8 af[4], bfr[4];
      #pragma unroll
      for (int i = 0; i < 4; i++) {
        int ra = wr * 64 + i * 16 + lrow;
        int sa = lq ^ (ra & 3);
        af[i] = *(const bf16x8*)&As[cur][ra * BKt + (sa << 3)];
        int rb = wc * 64 + i * 16 + lrow;
        int sb2 = lq ^ (rb & 3);
        bfr[i] = *(const bf16x8*)&Bs[cur][rb * BKt + (sb2 << 3)];
      }
      __builtin_amdgcn_s_setprio(1);
      #pragma unroll
      for (int mi = 0; mi < 4; mi++)
        #pragma unroll
        for (int ni = 0; ni < 4; ni++)
          acc[mi][ni] = __builtin_amdgcn_mfma_f32_16x16x32_bf16(af[mi], bfr[ni], acc[mi][ni], 0, 0, 0);
      __builtin_amdgcn_s_setprio(0);
    }
    __builtin_amdgcn_s_barrier();       // all waves done reading buffer cur
    if (t + 2 < NT) stage(cur, (t + 2) * BKt);   // buffer released by barrier
  }
  if (gkregion) {
    // gkbeta epilogue: cols 0..11 gk, 12..23 beta, rest discarded.
    #pragma unroll
    for (int mi = 0; mi < 4; mi++)
      #pragma unroll
      for (int ni = 0; ni < 4; ni++)
        #pragma unroll
        for (int r = 0; r < 4; r++) {
          int rr = row0 + wr * 64 + mi * 16 + lq * 4 + r;
          int cc = wc * 64 + ni * 16 + lrow;
          float v = acc[mi][ni][r];
          if (cc < 12) {
            float tt = v + dtf[cc];
            float sp = (tt > 20.f) ? tt : log1pf(__expf(tt));
            gkb[(size_t)rr * NHh + cc] = -__expf(A_logf[cc]) * sp;
          } else if (cc < 24) {
            betab[(size_t)rr * NHh + (cc - 12)] = sigmoidf_(v + bbf[cc - 12]);
          }
        }
    return;
  }
  bool f32 = (f32mode == 1) || (f32mode == 2 && *flag != 0);
  #pragma unroll
  for (int mi = 0; mi < 4; mi++)
    #pragma unroll
    for (int ni = 0; ni < 4; ni++)
      #pragma unroll
      for (int r = 0; r < 4; r++) {
        int rr = row0 + wr * 64 + mi * 16 + lq * 4 + r;
        int cc = col0 + wc * 64 + ni * 16 + lrow;
        float v = acc[mi][ni][r];
        if (f32) ((float*)Cg)[(size_t)rr * N + cc] = v;
        else     Cb[(size_t)rr * Nst + cc] = f2bf(v);
      }
}

// ---------- ALL causal dwconvs in ONE launch ----------
// Per row: 384 work-threads = 96 q (8ch, l2norm) + 96 k (8ch, l2norm) + 192 v (8ch).
__global__ void conv_all(const unsigned short* __restrict__ qkraw,
                         const unsigned short* __restrict__ vraw,
                         const float* __restrict__ cqf, const float* __restrict__ ckf,
                         const float* __restrict__ cvf,
                         unsigned short* __restrict__ qb, unsigned short* __restrict__ kb,
                         unsigned short* __restrict__ vb) {
  int idx = blockIdx.x * 256 + threadIdx.x;
  int row = idx / 384, w = idx - row * 384;
  int l = row & (L_ - 1);
  if (w < 192) {
    int isk = (w >= 96) ? 1 : 0;
    int c = (w - isk * 96) * 8;
    const float* wt = isk ? ckf : cqf;
    const unsigned short* base = qkraw + (size_t)row * 1536 + isk * KD + c;
    float acc[8] = {};
    #pragma unroll
    for (int j = 0; j < 4; j++) {
      int ll = l - 3 + j;
      if (ll >= 0) {
        u16x8 v = *(const u16x8*)(base + (ptrdiff_t)(j - 3) * 1536);
        f4v w0 = *(const f4v*)&wt[j * KD + c];
        f4v w1 = *(const f4v*)&wt[j * KD + c + 4];
        #pragma unroll
        for (int e = 0; e < 4; e++) acc[e] += bf2f(v[e]) * w0[e];
        #pragma unroll
        for (int e = 0; e < 4; e++) acc[4 + e] += bf2f(v[4 + e]) * w1[e];
      }
    }
    float x[8], ss = 0.f;
    #pragma unroll
    for (int e = 0; e < 8; e++) {
      float a = acc[e];
      x[e] = a * sigmoidf_(a);
      ss += x[e] * x[e];
    }
    #pragma unroll
    for (int off = 1; off <= 4; off <<= 1) ss += __shfl_xor(ss, off);
    float inv = 1.f / fmaxf(sqrtf(ss), 1e-12f);
    u16x8 o;
    #pragma unroll
    for (int e = 0; e < 8; e++) o[e] = f2bf(x[e] * inv);
    unsigned short* dst = (isk ? kb : qb) + (size_t)row * KD + c;
    *(u16x8*)dst = o;
  } else {
    int c = (w - 192) * 8;
    const unsigned short* base = vraw + (size_t)row * VD + c;
    float acc[8] = {};
    #pragma unroll
    for (int j = 0; j < 4; j++) {
      int ll = l - 3 + j;
      if (ll >= 0) {
        u16x8 v = *(const u16x8*)(base + (ptrdiff_t)(j - 3) * VD);
        f4v w0 = *(const f4v*)&cvf[j * VD + c];
        f4v w1 = *(const f4v*)&cvf[j * VD + c + 4];
        #pragma unroll
        for (int e = 0; e < 4; e++) acc[e] += bf2f(v[e]) * w0[e];
        #pragma unroll
        for (int e = 0; e < 4; e++) acc[4 + e] += bf2f(v[4 + e]) * w1[e];
      }
    }
    u16x8 o;
    #pragma unroll
    for (int e = 0; e < 8; e++) {
      float a = acc[e];
      o[e] = f2bf(a * sigmoidf_(a));
    }
    *(u16x8*)&vb[(size_t)row * VD + c] = o;
  }
}

// ================= CHUNKED GATED DELTA RULE =================
// ---------- Phase 1: per-chunk precompute (parallel, 1536 blocks) ----------
__global__ __launch_bounds__(256) void phase1_kernel(
    const unsigned short* __restrict__ kb, const unsigned short* __restrict__ vb,
    const float* __restrict__ gkb, const float* __restrict__ betab,
    unsigned short* __restrict__ U0g, unsigned short* __restrict__ Wmg,
    float* __restrict__ Gamg) {
  int cid = blockIdx.x;
  int c = cid & (NC - 1), bh = cid >> 5;
  int h = bh % NHh, b = bh / NHh;
  int bl0 = b * L_ + (c << 6);
  __shared__ __align__(16) unsigned short K_lds[64][72];
  __shared__ __align__(16) unsigned short Ab[64][72];
  __shared__ __align__(16) unsigned short Tb[64][72];
  __shared__ __align__(16) unsigned short TbT[64][72];
  __shared__ __align__(16) unsigned short Qt[64][40];
  __shared__ __align__(16) unsigned short Mpad[16][40];
  __shared__ __align__(16) unsigned short RHSt[192][72];
  __shared__ float G_lds[64], beta_lds[64], besc_lds[64];
  int tid = threadIdx.x;
  int wave = tid >> 6, lane = tid & 63, lq = lane >> 4, lrow = lane & 15;
  {
    u16x4 z = {};
    unsigned short* tb = &Tb[0][0];  unsigned short* tt = &TbT[0][0];
    for (int i = tid * 4; i < 64 * 72; i += 1024) {
      *(u16x4*)&tb[i] = z;  *(u16x4*)&tt[i] = z;
    }
    unsigned short* qt = &Qt[0][0];
    for (int i = tid * 4; i < 64 * 40; i += 1024) *(u16x4*)&qt[i] = z;
    if (tid < 160) *(u16x4*)&(&Mpad[0][0])[tid * 4] = z;
  }
  {
    int j = tid >> 2, d0 = (tid & 3) << 4;
    const ui4* src = (const ui4*)&kb[(size_t)(bl0 + j) * KD + h * 64 + d0];
    *(ui4*)&K_lds[j][d0]     = src[0];
    *(ui4*)&K_lds[j][d0 + 8] = src[1];
  }
  if (tid < 64) {
    float g  = gkb[(size_t)(bl0 + tid) * NHh + h];
    float bt = betab[(size_t)(bl0 + tid) * NHh + h];
    #pragma unroll
    for (int off = 1; off < 64; off <<= 1) {
      int src = lane - off;
      float y = __shfl(g, src < 0 ? 0 : src);
      if (lane >= off) g += y;
    }
    G_lds[tid]    = g;
    beta_lds[tid] = bt;
    besc_lds[tid] = bt * __expf(g);
    Gamg[(size_t)cid * 64 + tid] = g;
  }
  __syncthreads();
  #pragma unroll
  for (int mt = 0; mt < 4; mt++) {
    f32x4 acc = {};
    #pragma unroll
    for (int ks = 0; ks < 2; ks++) {
      bf16x8 a  = *(const bf16x8*)&K_lds[wave * 16 + lrow][ks * 32 + lq * 8];
      bf16x8 b2 = *(const bf16x8*)&K_lds[mt * 16 + lrow][ks * 32 + lq * 8];
      acc = __builtin_amdgcn_mfma_f32_16x16x32_bf16(a, b2, acc, 0, 0, 0);
    }
    #pragma unroll
    for (int r = 0; r < 4; r++) {
      int j = wave * 16 + lq * 4 + r, m = mt * 16 + lrow;
      Ab[j][m] = (m < j) ? f2bf(beta_lds[j] * __expf(G_lds[j] - G_lds[m]) * acc[r])
                         : (unsigned short)0;
    }
  }
  __syncthreads();
  if (wave == 0) {
    int blk = lq, cc = lrow, base = blk * 16;
    float t[16];
    t[0] = (cc == 0) ? 1.f : 0.f;
    #pragma unroll
    for (int j = 1; j < 16; j++) {
      float s = 0.f;
      #pragma unroll
      for (int m = 0; m < j; m++)
        s += bf2f(Ab[base + j][base + m]) * t[m];
      t[j] = ((cc == j) ? 1.f : 0.f) - s;
    }
    #pragma unroll
    for (int j = 0; j < 16; j++) {
      unsigned short bv = f2bf(t[j]);
      Tb[base + j][base + cc]  = bv;
      TbT[base + cc][base + j] = bv;
    }
  } else {
    int r = tid - 64;   // 0..191
    if (r < 128) {
      const unsigned short* vp = &vb[(size_t)bl0 * VD + h * 128 + r];
      for (int j = 0; j < 64; j++)
        RHSt[r][j] = f2bf(beta_lds[j] * bf2f(vp[(size_t)j * VD]));
    } else {
      int d = r - 128;
      for (int j = 0; j < 64; j++)
        RHSt[r][j] = f2bf(besc_lds[j] * bf2f(K_lds[j][d]));
    }
  }
  __syncthreads();
  #pragma unroll
  for (int lvl = 1; lvl < 4; lvl++) {
    {
      int m = tid >> 4, k = tid & 15;
      Ab[lvl * 16 + m][lvl * 16 + k] = 0;
      Mpad[m][k] = Tb[lvl * 16 + m][lvl * 16 + k];
    }
    __syncthreads();
    f32x4 accP = {};
    #pragma unroll
    for (int ks2 = 0; ks2 < 2; ks2++) {
      bf16x8 a  = *(const bf16x8*)&Ab[lvl * 16 + lrow][ks2 * 32 + lq * 8];
      bf16x8 b2 = *(const bf16x8*)&TbT[wave * 16 + lrow][ks2 * 32 + lq * 8];
      accP = __builtin_amdgcn_mfma_f32_16x16x32_bf16(a, b2, accP, 0, 0, 0);
    }
    {
      int col = wave * 16 + lrow;
      u16x4 qp;
      #pragma unroll
      for (int r = 0; r < 4; r++) {
        int krow = lq * 4 + r;
        float e = (col == lvl * 16 + krow) ? 1.f : 0.f;
        ((unsigned short*)&qp)[r] = f2bf(e - accP[r]);
      }
      *(u16x4*)&Qt[col][lq * 4] = qp;
    }
    __syncthreads();
    {
      bf16x8 am = *(const bf16x8*)&Mpad[lrow][lq * 8];
      bf16x8 bq = *(const bf16x8*)&Qt[wave * 16 + lrow][lq * 8];
      f32x4 accR = {};
      accR = __builtin_amdgcn_mfma_f32_16x16x32_bf16(am, bq, accR, 0, 0, 0);
      #pragma unroll
      for (int r = 0; r < 4; r++) {
        int row = lvl * 16 + lq * 4 + r, col = wave * 16 + lrow;
        unsigned short bv = f2bf(accR[r]);
        Tb[row][col]  = bv;
        TbT[col][row] = bv;
      }
    }
    __syncthreads();
  }
  bf16x8 af0 = *(const bf16x8*)&Tb[wave * 16 + lrow][lq * 8];
  bf16x8 af1 = *(const bf16x8*)&Tb[wave * 16 + lrow][32 + lq * 8];
  #pragma unroll
  for (int nt = 0; nt < 12; nt++) {
    f32x4 acc = {};
    bf16x8 b0 = *(const bf16x8*)&RHSt[nt * 16 + lrow][lq * 8];
    bf16x8 b1 = *(const bf16x8*)&RHSt[nt * 16 + lrow][32 + lq * 8];
    acc = __builtin_amdgcn_mfma_f32_16x16x32_bf16(af0, b0, acc, 0, 0, 0);
    acc = __builtin_amdgcn_mfma_f32_16x16x32_bf16(af1, b1, acc, 0, 0, 0);
    #pragma unroll
    for (int r = 0; r < 4; r++) {
      int i = wave * 16 + lq * 4 + r;
      int col = nt * 16 + lrow;
      if (nt < 8) U0g[(size_t)cid * 8192 + i * 128 + col] = f2bf(acc[r]);
      else        Wmg[(size_t)cid * 4096 + i * 64 + (col - 128)] = f2bf(acc[r]);
    }
  }
}

// ---------- Phase 2: inter-chunk state recurrence, v-split (192 blocks) ----------
__global__ __launch_bounds__(256) void phase2_kernel(
    const unsigned short* __restrict__ kb,
    const unsigned short* __restrict__ U0g, const unsigned short* __restrict__ Wmg,
    const float* __restrict__ Gamg, unsigned short* __restrict__ P0g) {
  int blk = blockIdx.x;              // bh*4 + vc
  int vc = blk & 3, bh = blk >> 2;
  int h = bh % NHh, b = bh / NHh;
  __shared__ __align__(16) unsigned short P_bf[32][72];    // S0 slice [v][d]
  __shared__ __align__(16) unsigned short Wm_lds[64][72];  // [j][d]
  __shared__ __align__(16) unsigned short Ktmp[64][72];    // [j][d]
  __shared__ __align__(16) unsigned short KpT_lds[64][72]; // [d][j]
  __shared__ __align__(16) unsigned short U0_lds[64][40];  // [j][v32]
  __shared__ __align__(16) unsigned short UT_lds[32][72];  // [v][j]
  __shared__ float G2[64];
  int tid = threadIdx.x;
  int wave = tid >> 6, lane = tid & 63, lq = lane >> 4, lrow = lane & 15;
  int vt = wave & 1, dbase = (wave >> 1) * 2;
  f32x4 P[2] = {};
  int pj = tid >> 2, px = (tid & 3) << 4;   // Wm/K: 32B per thread
  int pv = (tid & 3) << 3;                  // U0: 16B per thread (8 shorts)
  ui4 pf_wm0, pf_wm1, pf_k0, pf_k1, pf_u0;
  float pf_g = 0.f;
  {
    size_t cid0 = (size_t)bh * NC;
    int bl0 = b * L_;
    pf_wm0 = *(const ui4*)&Wmg[cid0 * 4096 + pj * 64 + px];
    pf_wm1 = *(const ui4*)&Wmg[cid0 * 4096 + pj * 64 + px + 8];
    pf_k0  = *(const ui4*)&kb[(size_t)(bl0 + pj) * KD + h * 64 + px];
    pf_k1  = *(const ui4*)&kb[(size_t)(bl0 + pj) * KD + h * 64 + px + 8];
    pf_u0  = *(const ui4*)&U0g[cid0 * 8192 + pj * 128 + vc * 32 + pv];
    if (tid < 64) pf_g = Gamg[cid0 * 64 + tid];
  }
  for (int c = 0; c < NC; c++) {
    size_t cid = (size_t)bh * NC + c;
    #pragma unroll
    for (int di = 0; di < 2; di++)
      #pragma unroll
      for (int r = 0; r < 4; r++)
        P_bf[vt * 16 + lq * 4 + r][(dbase + di) * 16 + lrow] = f2bf(P[di][r]);
    *(ui4*)&Wm_lds[pj][px]     = pf_wm0;
    *(ui4*)&Wm_lds[pj][px + 8] = pf_wm1;
    *(ui4*)&Ktmp[pj][px]       = pf_k0;
    *(ui4*)&Ktmp[pj][px + 8]   = pf_k1;
    *(ui4*)&U0_lds[pj][pv]     = pf_u0;
    if (tid < 64) G2[tid] = pf_g;
    __syncthreads();
    float gend = __expf(G2[63]);
    {
      int v = tid >> 3, d8 = (tid & 7) << 3;
      *(ui4*)&P0g[cid * 8192 + (size_t)(vc * 32 + v) * 64 + d8] = *(const ui4*)&P_bf[v][d8];
    }
    if (c + 1 < NC) {
      size_t cid1 = cid + 1;
      int bl1 = b * L_ + ((c + 1) << 6);
      pf_wm0 = *(const ui4*)&Wmg[cid1 * 4096 + pj * 64 + px];
      pf_wm1 = *(const ui4*)&Wmg[cid1 * 4096 + pj * 64 + px + 8];
      pf_k0  = *(const ui4*)&kb[(size_t)(bl1 + pj) * KD + h * 64 + px];
      pf_k1  = *(const ui4*)&kb[(size_t)(bl1 + pj) * KD + h * 64 + px + 8];
      pf_u0  = *(const ui4*)&U0g[cid1 * 8192 + pj * 128 + vc * 32 + pv];
      if (tid < 64) pf_g = Gamg[cid1 * 64 + tid];
    }
    {
      int d = tid & 63, j0 = (tid >> 6) << 4;
      float Ge = G2[63];
      #pragma unroll
      for (int i = 0; i < 16; i++) {
        int j = j0 + i;
        KpT_lds[d][j] = f2bf(__expf(Ge - G2[j]) * bf2f(Ktmp[j][d]));
      }
    }
    #pragma unroll
    for (int vt2 = 0; vt2 < 2; vt2++) {
      f32x4 acc = {};
      #pragma unroll
      for (int ks2 = 0; ks2 < 2; ks2++) {
        bf16x8 a  = *(const bf16x8*)&Wm_lds[wave * 16 + lrow][ks2 * 32 + lq * 8];
        bf16x8 b2 = *(const bf16x8*)&P_bf[vt2 * 16 + lrow][ks2 * 32 + lq * 8];
        acc = __builtin_amdgcn_mfma_f32_16x16x32_bf16(a, b2, acc, 0, 0, 0);
      }
      u16x4 p;
      #pragma unroll
      for (int r = 0; r < 4; r++) {
        int j = wave * 16 + lq * 4 + r;
        ((unsigned short*)&p)[r] = f2bf(bf2f(U0_lds[j][vt2 * 16 + lrow]) - acc[r]);
      }
      *(u16x4*)&UT_lds[vt2 * 16 + lrow][wave * 16 + lq * 4] = p;
    }
    __syncthreads();
    #pragma unroll
    for (int di = 0; di < 2; di++) {
      f32x4 acc = P[di];
      #pragma unroll
      for (int r = 0; r < 4; r++) acc[r] *= gend;
      #pragma unroll
      for (int ks2 = 0; ks2 < 2; ks2++) {
        bf16x8 a  = *(const bf16x8*)&UT_lds[vt * 16 + lrow][ks2 * 32 + lq * 8];
        bf16x8 b2 = *(const bf16x8*)&KpT_lds[(dbase + di) * 16 + lrow][ks2 * 32 + lq * 8];
        acc = __builtin_amdgcn_mfma_f32_16x16x32_bf16(a, b2, acc, 0, 0, 0);
      }
      P[di] = acc;
    }
  }
}

// ---------- Phase 3: per-chunk output + FUSED rmsnorm/gate (1536 blocks) ----------
__global__ __launch_bounds__(256) void phase3_kernel(
    const unsigned short* __restrict__ qb, const unsigned short* __restrict__ kb,
    const unsigned short* __restrict__ U0g, const unsigned short* __restrict__ Wmg,
    const unsigned short* __restrict__ P0g, const float* __restrict__ Gamg,
    const unsigned short* __restrict__ gb, const float* __restrict__ gnw,
    unsigned short* __restrict__ o_raw) {
  int cid = blockIdx.x;
  int c = cid & (NC - 1), bh = cid >> 5;
  int h = bh % NHh, b = bh / NHh;
  int bl0 = b * L_ + (c << 6);
  __shared__ __align__(16) unsigned short Q_lds[64][72];
  __shared__ __align__(16) unsigned short K_lds[64][72];
  __shared__ __align__(16) unsigned short WM_lds[64][72];
  __shared__ __align__(16) unsigned short P0_lds[128][72];
  __shared__ __align__(16) unsigned short U0_lds[64][128];
  __shared__ __align__(16) unsigned short UT_lds[128][72];
  __shared__ float G_lds[64];
  int tid = threadIdx.x;
  int wave = tid >> 6, lane = tid & 63, lq = lane >> 4, lrow = lane & 15;
  // early g prefetch (consumed after UT build; hides HBM latency under MFMAs)
  ui4 gpre[4];
  float gnww[8];
  {
    int j = tid >> 2, c0 = (tid & 3) << 5;
    const ui4* gs = (const ui4*)&gb[(size_t)(bl0 + j) * VD + h * 128 + c0];
    gpre[0] = gs[0]; gpre[1] = gs[1]; gpre[2] = gs[2]; gpre[3] = gs[3];
    #pragma unroll
    for (int nt = 0; nt < 8; nt++) gnww[nt] = gnw[nt * 16 + lrow];
  }
  {
    int j = tid >> 2, d0 = (tid & 3) << 4;
    const ui4* qs = (const ui4*)&qb[(size_t)(bl0 + j) * KD + h * 64 + d0];
    *(ui4*)&Q_lds[j][d0] = qs[0];  *(ui4*)&Q_lds[j][d0 + 8] = qs[1];
    const ui4* ks = (const ui4*)&kb[(size_t)(bl0 + j) * KD + h * 64 + d0];
    *(ui4*)&K_lds[j][d0] = ks[0];  *(ui4*)&K_lds[j][d0 + 8] = ks[1];
    const ui4* ws = (const ui4*)&Wmg[(size_t)cid * 4096 + j * 64 + d0];
    *(ui4*)&WM_lds[j][d0] = ws[0]; *(ui4*)&WM_lds[j][d0 + 8] = ws[1];
    int v = tid >> 1, e0 = (tid & 1) << 5;
    const ui4* ps = (const ui4*)&P0g[(size_t)cid * 8192 + v * 64 + e0];
    *(ui4*)&P0_lds[v][e0]      = ps[0]; *(ui4*)&P0_lds[v][e0 + 8]  = ps[1];
    *(ui4*)&P0_lds[v][e0 + 16] = ps[2]; *(ui4*)&P0_lds[v][e0 + 24] = ps[3];
    int e1 = tid * 32;
    const ui4* us = (const ui4*)&U0g[(size_t)cid * 8192 + e1];
    ui4* ud = (ui4*)&U0_lds[0][e1];
    ud[0] = us[0]; ud[1] = us[1]; ud[2] = us[2]; ud[3] = us[3];
    if (tid < 64) G_lds[tid] = Gamg[(size_t)cid * 64 + tid];
  }
  __syncthreads();
  #pragma unroll
  for (int nt = 0; nt < 8; nt++) {
    f32x4 acc = {};
    #pragma unroll
    for (int ks2 = 0; ks2 < 2; ks2++) {
      bf16x8 a  = *(const bf16x8*)&WM_lds[wave * 16 + lrow][ks2 * 32 + lq * 8];
      bf16x8 b2 = *(const bf16x8*)&P0_lds[nt * 16 + lrow][ks2 * 32 + lq * 8];
      acc = __builtin_amdgcn_mfma_f32_16x16x32_bf16(a, b2, acc, 0, 0, 0);
    }
    u16x4 p;
    #pragma unroll
    for (int r = 0; r < 4; r++) {
      int j = wave * 16 + lq * 4 + r;
      ((unsigned short*)&p)[r] = f2bf(bf2f(U0_lds[j][nt * 16 + lrow]) - acc[r]);
    }
    *(u16x4*)&UT_lds[nt * 16 + lrow][wave * 16 + lq * 4] = p;
  }
  __syncthreads();
  // U0_lds is dead now -> park g there (reads happen after the next barrier)
  {
    int j = tid >> 2, c0 = (tid & 3) << 5;
    ui4* gd = (ui4*)&U0_lds[j][c0];
    gd[0] = gpre[0]; gd[1] = gpre[1]; gd[2] = gpre[2]; gd[3] = gpre[3];
  }
  #pragma unroll
  for (int mt = 0; mt < 4; mt++) {
    f32x4 acc = {};
    #pragma unroll
    for (int ks2 = 0; ks2 < 2; ks2++) {
      bf16x8 a  = *(const bf16x8*)&Q_lds[wave * 16 + lrow][ks2 * 32 + lq * 8];
      bf16x8 b2 = *(const bf16x8*)&K_lds[mt * 16 + lrow][ks2 * 32 + lq * 8];
      acc = __builtin_amdgcn_mfma_f32_16x16x32_bf16(a, b2, acc, 0, 0, 0);
    }
    #pragma unroll
    for (int r = 0; r < 4; r++) {
      int i = wave * 16 + lq * 4 + r, j = mt * 16 + lrow;
      WM_lds[i][j] = (j <= i) ? f2bf(__expf(G_lds[i] - G_lds[j]) * acc[r]) : (unsigned short)0;
    }
  }
  __syncthreads();
  float ov[8][4];
  float eg[4];
  #pragma unroll
  for (int r = 0; r < 4; r++) eg[r] = __expf(G_lds[wave * 16 + lq * 4 + r]);
  #pragma unroll
  for (int nt = 0; nt < 8; nt++) {
    f32x4 accO = {}, accS = {};
    #pragma unroll
    for (int ks2 = 0; ks2 < 2; ks2++) {
      bf16x8 aM = *(const bf16x8*)&WM_lds[wave * 16 + lrow][ks2 * 32 + lq * 8];
      bf16x8 bU = *(const bf16x8*)&UT_lds[nt * 16 + lrow][ks2 * 32 + lq * 8];
      accO = __builtin_amdgcn_mfma_f32_16x16x32_bf16(aM, bU, accO, 0, 0, 0);
      bf16x8 aQ = *(const bf16x8*)&Q_lds[wave * 16 + lrow][ks2 * 32 + lq * 8];
      bf16x8 bP = *(const bf16x8*)&P0_lds[nt * 16 + lrow][ks2 * 32 + lq * 8];
      accS = __builtin_amdgcn_mfma_f32_16x16x32_bf16(aQ, bP, accS, 0, 0, 0);
    }
    #pragma unroll
    for (int r = 0; r < 4; r++) ov[nt][r] = accO[r] + eg[r] * accS[r];
  }
  // fused rmsnorm + gnorm_w * silu(g): per-row reduce over 128 cols
  float inv_[4];
  #pragma unroll
  for (int r = 0; r < 4; r++) {
    float ss = 0.f;
    #pragma unroll
    for (int nt = 0; nt < 8; nt++) ss += ov[nt][r] * ov[nt][r];
    #pragma unroll
    for (int off2 = 1; off2 <= 8; off2 <<= 1) ss += __shfl_xor(ss, off2);
    inv_[r] = rsqrtf(ss * (1.f / 128.f) + 1e-5f);
  }
  #pragma unroll
  for (int nt = 0; nt < 8; nt++) {
    #pragma unroll
    for (int r = 0; r < 4; r++) {
      int i = wave * 16 + lq * 4 + r;
      float gv = bf2f(U0_lds[i][nt * 16 + lrow]);
      float o = ov[nt][r] * inv_[r] * gnww[nt] * (gv * sigmoidf_(gv));
      o_raw[(size_t)(bl0 + i) * VD + h * 128 + nt * 16 + lrow] = f2bf(o);
    }
  }
}

// ---------- host launch ----------
extern "C" void kernel_launch(void* const* d_in, const int* in_sizes, int n_in,
                              void* d_out, int out_size, void* d_ws, size_t ws_size,
                              hipStream_t stream) {
  const void* hs      = d_in[0];
  const void* Wq      = d_in[1];
  const void* Wk      = d_in[2];
  const void* Wv      = d_in[3];
  const void* Wg      = d_in[4];
  const void* Wgk     = d_in[5];
  const void* Wb      = d_in[6];
  const void* bb      = d_in[7];
  const void* cq      = d_in[8];
  const void* ck      = d_in[9];
  const void* cv      = d_in[10];
  const void* A_log   = d_in[11];
  const void* gnorm_w = d_in[12];
  const void* Wo      = d_in[13];
  const void* dt_bias = d_in[14];

  char* wsB = (char*)d_ws;
  size_t off = 0;
  auto walloc = [&](size_t bytes) -> char* {
    char* p = wsB + off;
    off += (bytes + 1023) & ~(size_t)1023;
    return p;
  };
  int* flag = (int*)walloc(1024);
  // NOTE: WgkbT..WqT..WgT must stay contiguous (fused BT of [4736][1024], gk
  // region FIRST); all sizes are multiples of 1024 so walloc adds no padding.
  unsigned short* WgkbT = (unsigned short*)walloc((size_t)128 * H_ * 2);
  unsigned short* WqT   = (unsigned short*)walloc((size_t)KD * H_ * 2);
  unsigned short* WkT   = (unsigned short*)walloc((size_t)KD * H_ * 2);
  unsigned short* WvT   = (unsigned short*)walloc((size_t)VD * H_ * 2);
  unsigned short* WgT   = (unsigned short*)walloc((size_t)VD * H_ * 2);
  unsigned short* WoT   = (unsigned short*)walloc((size_t)H_ * VD * 2);
  float* cqf   = (float*)walloc((size_t)KD * 4 * 4);
  float* ckf   = (float*)walloc((size_t)KD * 4 * 4);
  float* cvf   = (float*)walloc((size_t)VD * 4 * 4);
  float* bbf   = (float*)walloc(NHh * 4);
  float* A_logf= (float*)walloc(NHh * 4);
  float* dtf   = (float*)walloc(NHh * 4);
  float* gnwf  = (float*)walloc(DVh * 4);
  float* gkb   = (float*)walloc((size_t)M_ * NHh * 4);
  float* betab = (float*)walloc((size_t)M_ * NHh * 4);
  float* Gamg  = (float*)walloc((size_t)NCID * 64 * 4);
  unsigned short* c_hs  = (unsigned short*)walloc((size_t)M_ * H_ * 2);
  // qkraw/vraw/gbuf must stay contiguous (fused GEMM C routing).
  unsigned short* qkraw = (unsigned short*)walloc((size_t)M_ * 1536 * 2);
  unsigned short* vraw  = (unsigned short*)walloc((size_t)M_ * VD * 2);
  unsigned short* gbuf  = (unsigned short*)walloc((size_t)M_ * VD * 2);
  unsigned short* qb    = (unsigned short*)walloc((size_t)M_ * KD * 2);
  unsigned short* kb    = (unsigned short*)walloc((size_t)M_ * KD * 2);
  unsigned short* vb    = (unsigned short*)walloc((size_t)M_ * VD * 2);
  // overlays (safe by launch order):
  unsigned short* Wmg   = c_hs;
  unsigned short* U0g   = qkraw;
  unsigned short* o_raw = vraw;
  unsigned short* P0g   = vb;

  // 0. dtype detection + canonicalization (transposes + hs convert in ONE launch)
  detect_dtype<<<1, 256, 0, stream>>>((const unsigned short*)hs, flag);
  convert_small<<<dim3(24, 7), 256, 0, stream>>>(cq, ck, cv, bb, A_log, dt_bias, gnorm_w,
                                                 cqf, ckf, cvf, bbf, A_logf, dtf, gnwf, flag);
  transpose_all<<<14400, 256, 0, stream>>>(Wq, Wk, Wv, Wg, Wgk, Wb, Wo,
                                           WqT, WkT, WvT, WgT, WgkbT, WgkbT + 12 * H_, WoT,
                                           hs, c_hs, flag);

  // 1. fused gkbeta|q|k|v|g projection: BT = [WgkbT;WqT;WkT;WvT;WgT] = [4736][1024];
  //    col tile y=0 runs the gkbeta epilogue (dispatched FIRST -> hidden under grid),
  //    cols [128,4736) routed per 1536-col region into qkraw/vraw/gbuf.
  gemm_bt<<<dim3(M_ / 256, 4736 / 128), 512, 0, stream>>>(c_hs, WgkbT, qkraw, M_, 4736, H_, 3, flag,
                                                          bbf, A_logf, dtf, gkb, betab);

  // 2. all convs (q+k l2norm, v) in one launch: 384 work-threads/row
  conv_all<<<(M_ * 384) / 256, 256, 0, stream>>>(qkraw, vraw, cqf, ckf, cvf, qb, kb, vb);

  // 3. chunked gated delta rule (phase3 fuses rmsnorm + swish gate)
  phase1_kernel<<<NCID, 256, 0, stream>>>(kb, vb, gkb, betab, U0g, Wmg, Gamg);
  phase2_kernel<<<B_ * NHh * 4, 256, 0, stream>>>(kb, U0g, Wmg, Gamg, P0g);
  phase3_kernel<<<NCID, 256, 0, stream>>>(qb, kb, U0g, Wmg, P0g, Gamg, gbuf, gnwf, o_raw);

  // 4. output projection (dtype-flag-selected store)
  gemm_bt<<<dim3(M_ / 256, H_ / 128), 512, 0, stream>>>(o_raw, WoT, d_out, M_, H_, VD, 2, flag,
                                                        nullptr, nullptr, nullptr, nullptr, nullptr);
}

// Round 11
// 410.235 us; speedup vs baseline: 1.0140x; 1.0140x over previous
//
#include <hip/hip_runtime.h>

// ---------- problem constants ----------
#define B_   4
#define L_   2048
#define H_   1024
#define KD   768
#define VD   1536
#define NHh  12
#define DKh  64
#define DVh  128
#define M_   (B_ * L_)   // 8192 rows
#define NC   32          // chunks per sequence (L/64)
#define NCID (B_ * NHh * NC)  // 1536

using bf16x8 = __attribute__((ext_vector_type(8))) __bf16;
using f32x4  = __attribute__((ext_vector_type(4))) float;
using ui4    = __attribute__((ext_vector_type(4))) unsigned int;
using f4v    = __attribute__((ext_vector_type(4))) float;
using u16x4  = __attribute__((ext_vector_type(4))) unsigned short;
using u16x8  = __attribute__((ext_vector_type(8))) unsigned short;

__device__ __forceinline__ float bf2f(unsigned short u) {
  unsigned int x = ((unsigned int)u) << 16;
  return __builtin_bit_cast(float, x);
}
__device__ __forceinline__ unsigned short f2bf(float f) {
  unsigned int u = __builtin_bit_cast(unsigned int, f);
  u += 0x7fffu + ((u >> 16) & 1u);
  return (unsigned short)(u >> 16);
}
__device__ __forceinline__ float sigmoidf_(float x) { return 1.f / (1.f + __expf(-x)); }

// async global->LDS DMA, 16B per lane; lds dest must be wave-uniform base (+lane*16 implicit)
__device__ __forceinline__ void async_copy16(const unsigned short* __restrict__ g,
                                             unsigned short* l) {
  __builtin_amdgcn_global_load_lds((const __attribute__((address_space(1))) unsigned int*)g,
                                   (__attribute__((address_space(3))) unsigned int*)l, 16, 0, 0);
}

// ---------- dtype detector: flag=1 if inputs are fp32, 0 if bf16 ----------
__global__ void detect_dtype(const unsigned short* __restrict__ hs, int* __restrict__ flag) {
  int tid = threadIdx.x;  // 256 threads
  int cnt = 0;
  for (int i = tid; i < 1024; i += 256) {
    int e = (hs[i] >> 7) & 0xFF;
    if (e >= 134) cnt++;
  }
  #pragma unroll
  for (int off = 32; off; off >>= 1) cnt += __shfl_xor(cnt, off);
  __shared__ int red[4];
  if ((tid & 63) == 0) red[tid >> 6] = cnt;
  __syncthreads();
  if (tid == 0) *flag = (red[0] + red[1] + red[2] + red[3] > 100) ? 1 : 0;
}

// ---------- convert 7 small arrays -> canonical fp32 ----------
// conv weights (a=0,1,2) are additionally TRANSPOSED: in [C][4] -> out [4][C]
__global__ void convert_small(const void* s0, const void* s1, const void* s2,
                              const void* s3, const void* s4, const void* s5, const void* s6,
                              float* d0, float* d1, float* d2, float* d3, float* d4,
                              float* d5, float* d6, const int* __restrict__ flag) {
  const int sizes[7] = {KD * 4, KD * 4, VD * 4, NHh, NHh, NHh, DVh};
  int a = blockIdx.y;
  const void* s; float* d;
  switch (a) {
    case 0: s = s0; d = d0; break;  case 1: s = s1; d = d1; break;
    case 2: s = s2; d = d2; break;  case 3: s = s3; d = d3; break;
    case 4: s = s4; d = d4; break;  case 5: s = s5; d = d5; break;
    default: s = s6; d = d6; break;
  }
  int i = blockIdx.x * 256 + threadIdx.x;
  if (i >= sizes[a]) return;
  float v = (*flag) ? ((const float*)s)[i] : bf2f(((const unsigned short*)s)[i]);
  if (a < 3) {
    int C = (a == 2) ? VD : KD;
    d[(i & 3) * C + (i >> 2)] = v;   // transposed [j][c]
  } else {
    d[i] = v;
  }
}

// ---------- ALL weight transposes + hs canonicalization in ONE launch ----------
// blocks [0,6208): 32x32 transpose tiles:
//   Wq 768 | Wk 768 | Wv 1536 | Wg 1536 | Wgk 32 | Wb 32 | Wo 1536
// blocks [6208,14400): hidden_states convert/copy (4 elems x 256 thr each)
__global__ void transpose_all(
    const void* s0, const void* s1, const void* s2, const void* s3,
    const void* s4, const void* s5, const void* s6,
    unsigned short* d0, unsigned short* d1, unsigned short* d2, unsigned short* d3,
    unsigned short* d4, unsigned short* d5, unsigned short* d6,
    const void* __restrict__ hs, unsigned short* __restrict__ c_hs,
    const int* __restrict__ flag) {
  int t = blockIdx.x;
  if (t >= 6208) {
    size_t i = ((size_t)(t - 6208) * 256 + threadIdx.x) * 4;
    if (*flag) {
      f4v v = *(const f4v*)((const float*)hs + i);
      u16x4 o;
      o.x = f2bf(v[0]); o.y = f2bf(v[1]); o.z = f2bf(v[2]); o.w = f2bf(v[3]);
      *(u16x4*)(c_hs + i) = o;
    } else {
      *(u16x4*)(c_hs + i) = *(const u16x4*)((const unsigned short*)hs + i);
    }
    return;
  }
  __shared__ unsigned short tile[32][33];
  const void* in; unsigned short* out; int R, C, ntx, tt;
  if (t < 768)       { in = s0; out = d0; R = 1024; C = 768;  ntx = 24; tt = t; }
  else if (t < 1536) { in = s1; out = d1; R = 1024; C = 768;  ntx = 24; tt = t - 768; }
  else if (t < 3072) { in = s2; out = d2; R = 1024; C = 1536; ntx = 48; tt = t - 1536; }
  else if (t < 4608) { in = s3; out = d3; R = 1024; C = 1536; ntx = 48; tt = t - 3072; }
  else if (t < 4640) { in = s4; out = d4; R = 1024; C = 12;   ntx = 1;  tt = t - 4608; }
  else if (t < 4672) { in = s5; out = d5; R = 1024; C = 12;   ntx = 1;  tt = t - 4640; }
  else               { in = s6; out = d6; R = 1536; C = 1024; ntx = 32; tt = t - 4672; }
  int f = *flag;
  int bx = tt % ntx, by = tt / ntx;
  int c0 = bx * 32, r0 = by * 32;
  int tx = threadIdx.x & 31, ty = threadIdx.x >> 5;
  #pragma unroll
  for (int i = 0; i < 32; i += 8) {
    int r = r0 + ty + i, c = c0 + tx;
    unsigned short v = 0;
    if (r < R && c < C)
      v = f ? f2bf(((const float*)in)[(size_t)r * C + c])
            : ((const unsigned short*)in)[(size_t)r * C + c];
    tile[ty + i][tx] = v;
  }
  __syncthreads();
  #pragma unroll
  for (int i = 0; i < 32; i += 8) {
    int c = c0 + ty + i, r = r0 + tx;
    if (c < C && r < R) out[(size_t)c * R + r] = tile[tx][ty + i];
  }
}

// ---------- MFMA GEMM: C[M,N] = A[M,K] * B[K,N], BT = B^T [N,K] ----------
// R11: R10 geometry (256x128 tile, BK=32, 512 thr, 48KB dbuf LDS, counted
// vmcnt(3)) with the SWIZZLE BUG FIXED. R10 post-mortem: slot = lq^(ra&3)
// gives only 2 slot values per row-parity -> 4-way bank conflict (9.7M/disp).
// Correct: slot = lq ^ ((ra>>1)&3) -> 8 distinct (parity,slot) bank-quads per
// 16 lanes = 2 lanes/quad = free (m136). Source pre-swizzle matches (rule #21).
// f32mode: 0=bf16, 1=f32, 2=flag-selected,
//          3=fused gkbeta|q|k|v|g routing over N=4736 (gk tile FIRST at y=0).
#define BMt 256
#define BNt 128
#define BKt 32

__global__ __launch_bounds__(512, 4) void gemm_bt(
    const unsigned short* __restrict__ Ag,
    const unsigned short* __restrict__ BTg,
    void* __restrict__ Cg,
    int M, int N, int K, int f32mode, const int* __restrict__ flag,
    const float* __restrict__ bbf, const float* __restrict__ A_logf,
    const float* __restrict__ dtf,
    float* __restrict__ gkb, float* __restrict__ betab) {
  __shared__ __align__(16) unsigned short As[2][BMt * BKt];   // 2 x 16KB
  __shared__ __align__(16) unsigned short Bs[2][BNt * BKt];   // 2 x 8KB
  const int tid = threadIdx.x;
  const int wave = tid >> 6, lane = tid & 63;
  const int wr = wave >> 1, wc = wave & 1;   // 4 x 2 wave grid: 64-row x 64-col per wave
  const int lrow = lane & 15, lq = lane >> 4;
  const int row0 = blockIdx.x * BMt;
  const int bcol0 = blockIdx.y * BNt;
  const bool gkregion = (f32mode == 3) && (bcol0 < BNt);
  // C routing
  unsigned short* Cb = (unsigned short*)Cg;
  int col0 = bcol0, Nst = N;
  if (f32mode == 3 && !gkregion) {
    int r3 = bcol0 - BNt;
    int region = r3 / 1536;
    Cb += (size_t)region * (size_t)M_ * 1536;
    col0 = r3 - region * 1536;
    Nst = 1536;
  }
  f32x4 acc[4][4] = {};
  // staging (per K-tile): A = 1024 16B-chunks (2/thread), B = 512 (1/thread).
  // chunk c: row r = c>>2, LDS slot u = c&3 holds global slot u^((r>>1)&3).
  auto stage = [&](int sb, int k0) {
    #pragma unroll
    for (int i = 0; i < 2; i++) {
      int c = i * 512 + tid;
      int r = c >> 2;
      int kk = ((c & 3) ^ ((r >> 1) & 3)) << 3;   // pre-swizzled source slot
      async_copy16(&Ag[(size_t)(row0 + r) * K + k0 + kk],
                   &As[sb][(i * 512 + wave * 64) * 8]);
    }
    {
      int c = tid;
      int r = c >> 2;
      int kk = ((c & 3) ^ ((r >> 1) & 3)) << 3;
      async_copy16(&BTg[(size_t)(bcol0 + r) * K + k0 + kk],
                   &Bs[sb][(wave * 64) * 8]);
    }
  };
  const int NT = K / BKt;
  stage(0, 0);
  stage(1, BKt);
  for (int t = 0; t < NT; t++) {
    // Drain only tile t's 3 loads (per-wave oldest); tile t+1's stay in flight.
    if (t + 1 < NT) asm volatile("s_waitcnt vmcnt(3)" ::: "memory");
    else            asm volatile("s_waitcnt vmcnt(0)" ::: "memory");
    __builtin_amdgcn_s_barrier();       // all waves' tile-t loads are in LDS
    const int cur = t & 1;
    {
      bf16x8 af[4], bfr[4];
      #pragma unroll
      for (int i = 0; i < 4; i++) {
        int ra = wr * 64 + i * 16 + lrow;
        int sa = lq ^ ((ra >> 1) & 3);
        af[i] = *(const bf16x8*)&As[cur][ra * BKt + (sa << 3)];
        int rb = wc * 64 + i * 16 + lrow;
        int sb2 = lq ^ ((rb >> 1) & 3);
        bfr[i] = *(const bf16x8*)&Bs[cur][rb * BKt + (sb2 << 3)];
      }
      __builtin_amdgcn_s_setprio(1);
      #pragma unroll
      for (int mi = 0; mi < 4; mi++)
        #pragma unroll
        for (int ni = 0; ni < 4; ni++)
          acc[mi][ni] = __builtin_amdgcn_mfma_f32_16x16x32_bf16(af[mi], bfr[ni], acc[mi][ni], 0, 0, 0);
      __builtin_amdgcn_s_setprio(0);
    }
    __builtin_amdgcn_s_barrier();       // all waves done reading buffer cur
    if (t + 2 < NT) stage(cur, (t + 2) * BKt);   // buffer released by barrier
  }
  if (gkregion) {
    // gkbeta epilogue: cols 0..11 gk, 12..23 beta, rest discarded.
    #pragma unroll
    for (int mi = 0; mi < 4; mi++)
      #pragma unroll
      for (int ni = 0; ni < 4; ni++)
        #pragma unroll
        for (int r = 0; r < 4; r++) {
          int rr = row0 + wr * 64 + mi * 16 + lq * 4 + r;
          int cc = wc * 64 + ni * 16 + lrow;
          float v = acc[mi][ni][r];
          if (cc < 12) {
            float tt = v + dtf[cc];
            float sp = (tt > 20.f) ? tt : log1pf(__expf(tt));
            gkb[(size_t)rr * NHh + cc] = -__expf(A_logf[cc]) * sp;
          } else if (cc < 24) {
            betab[(size_t)rr * NHh + (cc - 12)] = sigmoidf_(v + bbf[cc - 12]);
          }
        }
    return;
  }
  bool f32 = (f32mode == 1) || (f32mode == 2 && *flag != 0);
  #pragma unroll
  for (int mi = 0; mi < 4; mi++)
    #pragma unroll
    for (int ni = 0; ni < 4; ni++)
      #pragma unroll
      for (int r = 0; r < 4; r++) {
        int rr = row0 + wr * 64 + mi * 16 + lq * 4 + r;
        int cc = col0 + wc * 64 + ni * 16 + lrow;
        float v = acc[mi][ni][r];
        if (f32) ((float*)Cg)[(size_t)rr * N + cc] = v;
        else     Cb[(size_t)rr * Nst + cc] = f2bf(v);
      }
}

// ---------- ALL causal dwconvs in ONE launch ----------
// Per row: 384 work-threads = 96 q (8ch, l2norm) + 96 k (8ch, l2norm) + 192 v (8ch).
__global__ void conv_all(const unsigned short* __restrict__ qkraw,
                         const unsigned short* __restrict__ vraw,
                         const float* __restrict__ cqf, const float* __restrict__ ckf,
                         const float* __restrict__ cvf,
                         unsigned short* __restrict__ qb, unsigned short* __restrict__ kb,
                         unsigned short* __restrict__ vb) {
  int idx = blockIdx.x * 256 + threadIdx.x;
  int row = idx / 384, w = idx - row * 384;
  int l = row & (L_ - 1);
  if (w < 192) {
    int isk = (w >= 96) ? 1 : 0;
    int c = (w - isk * 96) * 8;
    const float* wt = isk ? ckf : cqf;
    const unsigned short* base = qkraw + (size_t)row * 1536 + isk * KD + c;
    float acc[8] = {};
    #pragma unroll
    for (int j = 0; j < 4; j++) {
      int ll = l - 3 + j;
      if (ll >= 0) {
        u16x8 v = *(const u16x8*)(base + (ptrdiff_t)(j - 3) * 1536);
        f4v w0 = *(const f4v*)&wt[j * KD + c];
        f4v w1 = *(const f4v*)&wt[j * KD + c + 4];
        #pragma unroll
        for (int e = 0; e < 4; e++) acc[e] += bf2f(v[e]) * w0[e];
        #pragma unroll
        for (int e = 0; e < 4; e++) acc[4 + e] += bf2f(v[4 + e]) * w1[e];
      }
    }
    float x[8], ss = 0.f;
    #pragma unroll
    for (int e = 0; e < 8; e++) {
      float a = acc[e];
      x[e] = a * sigmoidf_(a);
      ss += x[e] * x[e];
    }
    #pragma unroll
    for (int off = 1; off <= 4; off <<= 1) ss += __shfl_xor(ss, off);
    float inv = 1.f / fmaxf(sqrtf(ss), 1e-12f);
    u16x8 o;
    #pragma unroll
    for (int e = 0; e < 8; e++) o[e] = f2bf(x[e] * inv);
    unsigned short* dst = (isk ? kb : qb) + (size_t)row * KD + c;
    *(u16x8*)dst = o;
  } else {
    int c = (w - 192) * 8;
    const unsigned short* base = vraw + (size_t)row * VD + c;
    float acc[8] = {};
    #pragma unroll
    for (int j = 0; j < 4; j++) {
      int ll = l - 3 + j;
      if (ll >= 0) {
        u16x8 v = *(const u16x8*)(base + (ptrdiff_t)(j - 3) * VD);
        f4v w0 = *(const f4v*)&cvf[j * VD + c];
        f4v w1 = *(const f4v*)&cvf[j * VD + c + 4];
        #pragma unroll
        for (int e = 0; e < 4; e++) acc[e] += bf2f(v[e]) * w0[e];
        #pragma unroll
        for (int e = 0; e < 4; e++) acc[4 + e] += bf2f(v[4 + e]) * w1[e];
      }
    }
    u16x8 o;
    #pragma unroll
    for (int e = 0; e < 8; e++) {
      float a = acc[e];
      o[e] = f2bf(a * sigmoidf_(a));
    }
    *(u16x8*)&vb[(size_t)row * VD + c] = o;
  }
}

// ================= CHUNKED GATED DELTA RULE =================
// ---------- Phase 1: per-chunk precompute (parallel, 1536 blocks) ----------
__global__ __launch_bounds__(256) void phase1_kernel(
    const unsigned short* __restrict__ kb, const unsigned short* __restrict__ vb,
    const float* __restrict__ gkb, const float* __restrict__ betab,
    unsigned short* __restrict__ U0g, unsigned short* __restrict__ Wmg,
    float* __restrict__ Gamg) {
  int cid = blockIdx.x;
  int c = cid & (NC - 1), bh = cid >> 5;
  int h = bh % NHh, b = bh / NHh;
  int bl0 = b * L_ + (c << 6);
  __shared__ __align__(16) unsigned short K_lds[64][72];
  __shared__ __align__(16) unsigned short Ab[64][72];
  __shared__ __align__(16) unsigned short Tb[64][72];
  __shared__ __align__(16) unsigned short TbT[64][72];
  __shared__ __align__(16) unsigned short Qt[64][40];
  __shared__ __align__(16) unsigned short Mpad[16][40];
  __shared__ __align__(16) unsigned short RHSt[192][72];
  __shared__ float G_lds[64], beta_lds[64], besc_lds[64];
  int tid = threadIdx.x;
  int wave = tid >> 6, lane = tid & 63, lq = lane >> 4, lrow = lane & 15;
  {
    u16x4 z = {};
    unsigned short* tb = &Tb[0][0];  unsigned short* tt = &TbT[0][0];
    for (int i = tid * 4; i < 64 * 72; i += 1024) {
      *(u16x4*)&tb[i] = z;  *(u16x4*)&tt[i] = z;
    }
    unsigned short* qt = &Qt[0][0];
    for (int i = tid * 4; i < 64 * 40; i += 1024) *(u16x4*)&qt[i] = z;
    if (tid < 160) *(u16x4*)&(&Mpad[0][0])[tid * 4] = z;
  }
  {
    int j = tid >> 2, d0 = (tid & 3) << 4;
    const ui4* src = (const ui4*)&kb[(size_t)(bl0 + j) * KD + h * 64 + d0];
    *(ui4*)&K_lds[j][d0]     = src[0];
    *(ui4*)&K_lds[j][d0 + 8] = src[1];
  }
  if (tid < 64) {
    float g  = gkb[(size_t)(bl0 + tid) * NHh + h];
    float bt = betab[(size_t)(bl0 + tid) * NHh + h];
    #pragma unroll
    for (int off = 1; off < 64; off <<= 1) {
      int src = lane - off;
      float y = __shfl(g, src < 0 ? 0 : src);
      if (lane >= off) g += y;
    }
    G_lds[tid]    = g;
    beta_lds[tid] = bt;
    besc_lds[tid] = bt * __expf(g);
    Gamg[(size_t)cid * 64 + tid] = g;
  }
  __syncthreads();
  #pragma unroll
  for (int mt = 0; mt < 4; mt++) {
    f32x4 acc = {};
    #pragma unroll
    for (int ks = 0; ks < 2; ks++) {
      bf16x8 a  = *(const bf16x8*)&K_lds[wave * 16 + lrow][ks * 32 + lq * 8];
      bf16x8 b2 = *(const bf16x8*)&K_lds[mt * 16 + lrow][ks * 32 + lq * 8];
      acc = __builtin_amdgcn_mfma_f32_16x16x32_bf16(a, b2, acc, 0, 0, 0);
    }
    #pragma unroll
    for (int r = 0; r < 4; r++) {
      int j = wave * 16 + lq * 4 + r, m = mt * 16 + lrow;
      Ab[j][m] = (m < j) ? f2bf(beta_lds[j] * __expf(G_lds[j] - G_lds[m]) * acc[r])
                         : (unsigned short)0;
    }
  }
  __syncthreads();
  if (wave == 0) {
    int blk = lq, cc = lrow, base = blk * 16;
    float t[16];
    t[0] = (cc == 0) ? 1.f : 0.f;
    #pragma unroll
    for (int j = 1; j < 16; j++) {
      float s = 0.f;
      #pragma unroll
      for (int m = 0; m < j; m++)
        s += bf2f(Ab[base + j][base + m]) * t[m];
      t[j] = ((cc == j) ? 1.f : 0.f) - s;
    }
    #pragma unroll
    for (int j = 0; j < 16; j++) {
      unsigned short bv = f2bf(t[j]);
      Tb[base + j][base + cc]  = bv;
      TbT[base + cc][base + j] = bv;
    }
  } else {
    int r = tid - 64;   // 0..191
    if (r < 128) {
      const unsigned short* vp = &vb[(size_t)bl0 * VD + h * 128 + r];
      for (int j = 0; j < 64; j++)
        RHSt[r][j] = f2bf(beta_lds[j] * bf2f(vp[(size_t)j * VD]));
    } else {
      int d = r - 128;
      for (int j = 0; j < 64; j++)
        RHSt[r][j] = f2bf(besc_lds[j] * bf2f(K_lds[j][d]));
    }
  }
  __syncthreads();
  #pragma unroll
  for (int lvl = 1; lvl < 4; lvl++) {
    {
      int m = tid >> 4, k = tid & 15;
      Ab[lvl * 16 + m][lvl * 16 + k] = 0;
      Mpad[m][k] = Tb[lvl * 16 + m][lvl * 16 + k];
    }
    __syncthreads();
    f32x4 accP = {};
    #pragma unroll
    for (int ks2 = 0; ks2 < 2; ks2++) {
      bf16x8 a  = *(const bf16x8*)&Ab[lvl * 16 + lrow][ks2 * 32 + lq * 8];
      bf16x8 b2 = *(const bf16x8*)&TbT[wave * 16 + lrow][ks2 * 32 + lq * 8];
      accP = __builtin_amdgcn_mfma_f32_16x16x32_bf16(a, b2, accP, 0, 0, 0);
    }
    {
      int col = wave * 16 + lrow;
      u16x4 qp;
      #pragma unroll
      for (int r = 0; r < 4; r++) {
        int krow = lq * 4 + r;
        float e = (col == lvl * 16 + krow) ? 1.f : 0.f;
        ((unsigned short*)&qp)[r] = f2bf(e - accP[r]);
      }
      *(u16x4*)&Qt[col][lq * 4] = qp;
    }
    __syncthreads();
    {
      bf16x8 am = *(const bf16x8*)&Mpad[lrow][lq * 8];
      bf16x8 bq = *(const bf16x8*)&Qt[wave * 16 + lrow][lq * 8];
      f32x4 accR = {};
      accR = __builtin_amdgcn_mfma_f32_16x16x32_bf16(am, bq, accR, 0, 0, 0);
      #pragma unroll
      for (int r = 0; r < 4; r++) {
        int row = lvl * 16 + lq * 4 + r, col = wave * 16 + lrow;
        unsigned short bv = f2bf(accR[r]);
        Tb[row][col]  = bv;
        TbT[col][row] = bv;
      }
    }
    __syncthreads();
  }
  bf16x8 af0 = *(const bf16x8*)&Tb[wave * 16 + lrow][lq * 8];
  bf16x8 af1 = *(const bf16x8*)&Tb[wave * 16 + lrow][32 + lq * 8];
  #pragma unroll
  for (int nt = 0; nt < 12; nt++) {
    f32x4 acc = {};
    bf16x8 b0 = *(const bf16x8*)&RHSt[nt * 16 + lrow][lq * 8];
    bf16x8 b1 = *(const bf16x8*)&RHSt[nt * 16 + lrow][32 + lq * 8];
    acc = __builtin_amdgcn_mfma_f32_16x16x32_bf16(af0, b0, acc, 0, 0, 0);
    acc = __builtin_amdgcn_mfma_f32_16x16x32_bf16(af1, b1, acc, 0, 0, 0);
    #pragma unroll
    for (int r = 0; r < 4; r++) {
      int i = wave * 16 + lq * 4 + r;
      int col = nt * 16 + lrow;
      if (nt < 8) U0g[(size_t)cid * 8192 + i * 128 + col] = f2bf(acc[r]);
      else        Wmg[(size_t)cid * 4096 + i * 64 + (col - 128)] = f2bf(acc[r]);
    }
  }
}

// ---------- Phase 2: inter-chunk state recurrence, v-split (192 blocks) ----------
__global__ __launch_bounds__(256) void phase2_kernel(
    const unsigned short* __restrict__ kb,
    const unsigned short* __restrict__ U0g, const unsigned short* __restrict__ Wmg,
    const float* __restrict__ Gamg, unsigned short* __restrict__ P0g) {
  int blk = blockIdx.x;              // bh*4 + vc
  int vc = blk & 3, bh = blk >> 2;
  int h = bh % NHh, b = bh / NHh;
  __shared__ __align__(16) unsigned short P_bf[32][72];    // S0 slice [v][d]
  __shared__ __align__(16) unsigned short Wm_lds[64][72];  // [j][d]
  __shared__ __align__(16) unsigned short Ktmp[64][72];    // [j][d]
  __shared__ __align__(16) unsigned short KpT_lds[64][72]; // [d][j]
  __shared__ __align__(16) unsigned short U0_lds[64][40];  // [j][v32]
  __shared__ __align__(16) unsigned short UT_lds[32][72];  // [v][j]
  __shared__ float G2[64];
  int tid = threadIdx.x;
  int wave = tid >> 6, lane = tid & 63, lq = lane >> 4, lrow = lane & 15;
  int vt = wave & 1, dbase = (wave >> 1) * 2;
  f32x4 P[2] = {};
  int pj = tid >> 2, px = (tid & 3) << 4;   // Wm/K: 32B per thread
  int pv = (tid & 3) << 3;                  // U0: 16B per thread (8 shorts)
  ui4 pf_wm0, pf_wm1, pf_k0, pf_k1, pf_u0;
  float pf_g = 0.f;
  {
    size_t cid0 = (size_t)bh * NC;
    int bl0 = b * L_;
    pf_wm0 = *(const ui4*)&Wmg[cid0 * 4096 + pj * 64 + px];
    pf_wm1 = *(const ui4*)&Wmg[cid0 * 4096 + pj * 64 + px + 8];
    pf_k0  = *(const ui4*)&kb[(size_t)(bl0 + pj) * KD + h * 64 + px];
    pf_k1  = *(const ui4*)&kb[(size_t)(bl0 + pj) * KD + h * 64 + px + 8];
    pf_u0  = *(const ui4*)&U0g[cid0 * 8192 + pj * 128 + vc * 32 + pv];
    if (tid < 64) pf_g = Gamg[cid0 * 64 + tid];
  }
  for (int c = 0; c < NC; c++) {
    size_t cid = (size_t)bh * NC + c;
    #pragma unroll
    for (int di = 0; di < 2; di++)
      #pragma unroll
      for (int r = 0; r < 4; r++)
        P_bf[vt * 16 + lq * 4 + r][(dbase + di) * 16 + lrow] = f2bf(P[di][r]);
    *(ui4*)&Wm_lds[pj][px]     = pf_wm0;
    *(ui4*)&Wm_lds[pj][px + 8] = pf_wm1;
    *(ui4*)&Ktmp[pj][px]       = pf_k0;
    *(ui4*)&Ktmp[pj][px + 8]   = pf_k1;
    *(ui4*)&U0_lds[pj][pv]     = pf_u0;
    if (tid < 64) G2[tid] = pf_g;
    __syncthreads();
    float gend = __expf(G2[63]);
    {
      int v = tid >> 3, d8 = (tid & 7) << 3;
      *(ui4*)&P0g[cid * 8192 + (size_t)(vc * 32 + v) * 64 + d8] = *(const ui4*)&P_bf[v][d8];
    }
    if (c + 1 < NC) {
      size_t cid1 = cid + 1;
      int bl1 = b * L_ + ((c + 1) << 6);
      pf_wm0 = *(const ui4*)&Wmg[cid1 * 4096 + pj * 64 + px];
      pf_wm1 = *(const ui4*)&Wmg[cid1 * 4096 + pj * 64 + px + 8];
      pf_k0  = *(const ui4*)&kb[(size_t)(bl1 + pj) * KD + h * 64 + px];
      pf_k1  = *(const ui4*)&kb[(size_t)(bl1 + pj) * KD + h * 64 + px + 8];
      pf_u0  = *(const ui4*)&U0g[cid1 * 8192 + pj * 128 + vc * 32 + pv];
      if (tid < 64) pf_g = Gamg[cid1 * 64 + tid];
    }
    {
      int d = tid & 63, j0 = (tid >> 6) << 4;
      float Ge = G2[63];
      #pragma unroll
      for (int i = 0; i < 16; i++) {
        int j = j0 + i;
        KpT_lds[d][j] = f2bf(__expf(Ge - G2[j]) * bf2f(Ktmp[j][d]));
      }
    }
    #pragma unroll
    for (int vt2 = 0; vt2 < 2; vt2++) {
      f32x4 acc = {};
      #pragma unroll
      for (int ks2 = 0; ks2 < 2; ks2++) {
        bf16x8 a  = *(const bf16x8*)&Wm_lds[wave * 16 + lrow][ks2 * 32 + lq * 8];
        bf16x8 b2 = *(const bf16x8*)&P_bf[vt2 * 16 + lrow][ks2 * 32 + lq * 8];
        acc = __builtin_amdgcn_mfma_f32_16x16x32_bf16(a, b2, acc, 0, 0, 0);
      }
      u16x4 p;
      #pragma unroll
      for (int r = 0; r < 4; r++) {
        int j = wave * 16 + lq * 4 + r;
        ((unsigned short*)&p)[r] = f2bf(bf2f(U0_lds[j][vt2 * 16 + lrow]) - acc[r]);
      }
      *(u16x4*)&UT_lds[vt2 * 16 + lrow][wave * 16 + lq * 4] = p;
    }
    __syncthreads();
    #pragma unroll
    for (int di = 0; di < 2; di++) {
      f32x4 acc = P[di];
      #pragma unroll
      for (int r = 0; r < 4; r++) acc[r] *= gend;
      #pragma unroll
      for (int ks2 = 0; ks2 < 2; ks2++) {
        bf16x8 a  = *(const bf16x8*)&UT_lds[vt * 16 + lrow][ks2 * 32 + lq * 8];
        bf16x8 b2 = *(const bf16x8*)&KpT_lds[(dbase + di) * 16 + lrow][ks2 * 32 + lq * 8];
        acc = __builtin_amdgcn_mfma_f32_16x16x32_bf16(a, b2, acc, 0, 0, 0);
      }
      P[di] = acc;
    }
  }
}

// ---------- Phase 3: per-chunk output + FUSED rmsnorm/gate (1536 blocks) ----------
__global__ __launch_bounds__(256) void phase3_kernel(
    const unsigned short* __restrict__ qb, const unsigned short* __restrict__ kb,
    const unsigned short* __restrict__ U0g, const unsigned short* __restrict__ Wmg,
    const unsigned short* __restrict__ P0g, const float* __restrict__ Gamg,
    const unsigned short* __restrict__ gb, const float* __restrict__ gnw,
    unsigned short* __restrict__ o_raw) {
  int cid = blockIdx.x;
  int c = cid & (NC - 1), bh = cid >> 5;
  int h = bh % NHh, b = bh / NHh;
  int bl0 = b * L_ + (c << 6);
  __shared__ __align__(16) unsigned short Q_lds[64][72];
  __shared__ __align__(16) unsigned short K_lds[64][72];
  __shared__ __align__(16) unsigned short WM_lds[64][72];
  __shared__ __align__(16) unsigned short P0_lds[128][72];
  __shared__ __align__(16) unsigned short U0_lds[64][128];
  __shared__ __align__(16) unsigned short UT_lds[128][72];
  __shared__ float G_lds[64];
  int tid = threadIdx.x;
  int wave = tid >> 6, lane = tid & 63, lq = lane >> 4, lrow = lane & 15;
  // early g prefetch (consumed after UT build; hides HBM latency under MFMAs)
  ui4 gpre[4];
  float gnww[8];
  {
    int j = tid >> 2, c0 = (tid & 3) << 5;
    const ui4* gs = (const ui4*)&gb[(size_t)(bl0 + j) * VD + h * 128 + c0];
    gpre[0] = gs[0]; gpre[1] = gs[1]; gpre[2] = gs[2]; gpre[3] = gs[3];
    #pragma unroll
    for (int nt = 0; nt < 8; nt++) gnww[nt] = gnw[nt * 16 + lrow];
  }
  {
    int j = tid >> 2, d0 = (tid & 3) << 4;
    const ui4* qs = (const ui4*)&qb[(size_t)(bl0 + j) * KD + h * 64 + d0];
    *(ui4*)&Q_lds[j][d0] = qs[0];  *(ui4*)&Q_lds[j][d0 + 8] = qs[1];
    const ui4* ks = (const ui4*)&kb[(size_t)(bl0 + j) * KD + h * 64 + d0];
    *(ui4*)&K_lds[j][d0] = ks[0];  *(ui4*)&K_lds[j][d0 + 8] = ks[1];
    const ui4* ws = (const ui4*)&Wmg[(size_t)cid * 4096 + j * 64 + d0];
    *(ui4*)&WM_lds[j][d0] = ws[0]; *(ui4*)&WM_lds[j][d0 + 8] = ws[1];
    int v = tid >> 1, e0 = (tid & 1) << 5;
    const ui4* ps = (const ui4*)&P0g[(size_t)cid * 8192 + v * 64 + e0];
    *(ui4*)&P0_lds[v][e0]      = ps[0]; *(ui4*)&P0_lds[v][e0 + 8]  = ps[1];
    *(ui4*)&P0_lds[v][e0 + 16] = ps[2]; *(ui4*)&P0_lds[v][e0 + 24] = ps[3];
    int e1 = tid * 32;
    const ui4* us = (const ui4*)&U0g[(size_t)cid * 8192 + e1];
    ui4* ud = (ui4*)&U0_lds[0][e1];
    ud[0] = us[0]; ud[1] = us[1]; ud[2] = us[2]; ud[3] = us[3];
    if (tid < 64) G_lds[tid] = Gamg[(size_t)cid * 64 + tid];
  }
  __syncthreads();
  #pragma unroll
  for (int nt = 0; nt < 8; nt++) {
    f32x4 acc = {};
    #pragma unroll
    for (int ks2 = 0; ks2 < 2; ks2++) {
      bf16x8 a  = *(const bf16x8*)&WM_lds[wave * 16 + lrow][ks2 * 32 + lq * 8];
      bf16x8 b2 = *(const bf16x8*)&P0_lds[nt * 16 + lrow][ks2 * 32 + lq * 8];
      acc = __builtin_amdgcn_mfma_f32_16x16x32_bf16(a, b2, acc, 0, 0, 0);
    }
    u16x4 p;
    #pragma unroll
    for (int r = 0; r < 4; r++) {
      int j = wave * 16 + lq * 4 + r;
      ((unsigned short*)&p)[r] = f2bf(bf2f(U0_lds[j][nt * 16 + lrow]) - acc[r]);
    }
    *(u16x4*)&UT_lds[nt * 16 + lrow][wave * 16 + lq * 4] = p;
  }
  __syncthreads();
  // U0_lds is dead now -> park g there (reads happen after the next barrier)
  {
    int j = tid >> 2, c0 = (tid & 3) << 5;
    ui4* gd = (ui4*)&U0_lds[j][c0];
    gd[0] = gpre[0]; gd[1] = gpre[1]; gd[2] = gpre[2]; gd[3] = gpre[3];
  }
  #pragma unroll
  for (int mt = 0; mt < 4; mt++) {
    f32x4 acc = {};
    #pragma unroll
    for (int ks2 = 0; ks2 < 2; ks2++) {
      bf16x8 a  = *(const bf16x8*)&Q_lds[wave * 16 + lrow][ks2 * 32 + lq * 8];
      bf16x8 b2 = *(const bf16x8*)&K_lds[mt * 16 + lrow][ks2 * 32 + lq * 8];
      acc = __builtin_amdgcn_mfma_f32_16x16x32_bf16(a, b2, acc, 0, 0, 0);
    }
    #pragma unroll
    for (int r = 0; r < 4; r++) {
      int i = wave * 16 + lq * 4 + r, j = mt * 16 + lrow;
      WM_lds[i][j] = (j <= i) ? f2bf(__expf(G_lds[i] - G_lds[j]) * acc[r]) : (unsigned short)0;
    }
  }
  __syncthreads();
  float ov[8][4];
  float eg[4];
  #pragma unroll
  for (int r = 0; r < 4; r++) eg[r] = __expf(G_lds[wave * 16 + lq * 4 + r]);
  #pragma unroll
  for (int nt = 0; nt < 8; nt++) {
    f32x4 accO = {}, accS = {};
    #pragma unroll
    for (int ks2 = 0; ks2 < 2; ks2++) {
      bf16x8 aM = *(const bf16x8*)&WM_lds[wave * 16 + lrow][ks2 * 32 + lq * 8];
      bf16x8 bU = *(const bf16x8*)&UT_lds[nt * 16 + lrow][ks2 * 32 + lq * 8];
      accO = __builtin_amdgcn_mfma_f32_16x16x32_bf16(aM, bU, accO, 0, 0, 0);
      bf16x8 aQ = *(const bf16x8*)&Q_lds[wave * 16 + lrow][ks2 * 32 + lq * 8];
      bf16x8 bP = *(const bf16x8*)&P0_lds[nt * 16 + lrow][ks2 * 32 + lq * 8];
      accS = __builtin_amdgcn_mfma_f32_16x16x32_bf16(aQ, bP, accS, 0, 0, 0);
    }
    #pragma unroll
    for (int r = 0; r < 4; r++) ov[nt][r] = accO[r] + eg[r] * accS[r];
  }
  // fused rmsnorm + gnorm_w * silu(g): per-row reduce over 128 cols
  float inv_[4];
  #pragma unroll
  for (int r = 0; r < 4; r++) {
    float ss = 0.f;
    #pragma unroll
    for (int nt = 0; nt < 8; nt++) ss += ov[nt][r] * ov[nt][r];
    #pragma unroll
    for (int off2 = 1; off2 <= 8; off2 <<= 1) ss += __shfl_xor(ss, off2);
    inv_[r] = rsqrtf(ss * (1.f / 128.f) + 1e-5f);
  }
  #pragma unroll
  for (int nt = 0; nt < 8; nt++) {
    #pragma unroll
    for (int r = 0; r < 4; r++) {
      int i = wave * 16 + lq * 4 + r;
      float gv = bf2f(U0_lds[i][nt * 16 + lrow]);
      float o = ov[nt][r] * inv_[r] * gnww[nt] * (gv * sigmoidf_(gv));
      o_raw[(size_t)(bl0 + i) * VD + h * 128 + nt * 16 + lrow] = f2bf(o);
    }
  }
}

// ---------- host launch ----------
extern "C" void kernel_launch(void* const* d_in, const int* in_sizes, int n_in,
                              void* d_out, int out_size, void* d_ws, size_t ws_size,
                              hipStream_t stream) {
  const void* hs      = d_in[0];
  const void* Wq      = d_in[1];
  const void* Wk      = d_in[2];
  const void* Wv      = d_in[3];
  const void* Wg      = d_in[4];
  const void* Wgk     = d_in[5];
  const void* Wb      = d_in[6];
  const void* bb      = d_in[7];
  const void* cq      = d_in[8];
  const void* ck      = d_in[9];
  const void* cv      = d_in[10];
  const void* A_log   = d_in[11];
  const void* gnorm_w = d_in[12];
  const void* Wo      = d_in[13];
  const void* dt_bias = d_in[14];

  char* wsB = (char*)d_ws;
  size_t off = 0;
  auto walloc = [&](size_t bytes) -> char* {
    char* p = wsB + off;
    off += (bytes + 1023) & ~(size_t)1023;
    return p;
  };
  int* flag = (int*)walloc(1024);
  // NOTE: WgkbT..WqT..WgT must stay contiguous (fused BT of [4736][1024], gk
  // region FIRST); all sizes are multiples of 1024 so walloc adds no padding.
  unsigned short* WgkbT = (unsigned short*)walloc((size_t)128 * H_ * 2);
  unsigned short* WqT   = (unsigned short*)walloc((size_t)KD * H_ * 2);
  unsigned short* WkT   = (unsigned short*)walloc((size_t)KD * H_ * 2);
  unsigned short* WvT   = (unsigned short*)walloc((size_t)VD * H_ * 2);
  unsigned short* WgT   = (unsigned short*)walloc((size_t)VD * H_ * 2);
  unsigned short* WoT   = (unsigned short*)walloc((size_t)H_ * VD * 2);
  float* cqf   = (float*)walloc((size_t)KD * 4 * 4);
  float* ckf   = (float*)walloc((size_t)KD * 4 * 4);
  float* cvf   = (float*)walloc((size_t)VD * 4 * 4);
  float* bbf   = (float*)walloc(NHh * 4);
  float* A_logf= (float*)walloc(NHh * 4);
  float* dtf   = (float*)walloc(NHh * 4);
  float* gnwf  = (float*)walloc(DVh * 4);
  float* gkb   = (float*)walloc((size_t)M_ * NHh * 4);
  float* betab = (float*)walloc((size_t)M_ * NHh * 4);
  float* Gamg  = (float*)walloc((size_t)NCID * 64 * 4);
  unsigned short* c_hs  = (unsigned short*)walloc((size_t)M_ * H_ * 2);
  // qkraw/vraw/gbuf must stay contiguous (fused GEMM C routing).
  unsigned short* qkraw = (unsigned short*)walloc((size_t)M_ * 1536 * 2);
  unsigned short* vraw  = (unsigned short*)walloc((size_t)M_ * VD * 2);
  unsigned short* gbuf  = (unsigned short*)walloc((size_t)M_ * VD * 2);
  unsigned short* qb    = (unsigned short*)walloc((size_t)M_ * KD * 2);
  unsigned short* kb    = (unsigned short*)walloc((size_t)M_ * KD * 2);
  unsigned short* vb    = (unsigned short*)walloc((size_t)M_ * VD * 2);
  // overlays (safe by launch order):
  unsigned short* Wmg   = c_hs;
  unsigned short* U0g   = qkraw;
  unsigned short* o_raw = vraw;
  unsigned short* P0g   = vb;

  // 0. dtype detection + canonicalization (transposes + hs convert in ONE launch)
  detect_dtype<<<1, 256, 0, stream>>>((const unsigned short*)hs, flag);
  convert_small<<<dim3(24, 7), 256, 0, stream>>>(cq, ck, cv, bb, A_log, dt_bias, gnorm_w,
                                                 cqf, ckf, cvf, bbf, A_logf, dtf, gnwf, flag);
  transpose_all<<<14400, 256, 0, stream>>>(Wq, Wk, Wv, Wg, Wgk, Wb, Wo,
                                           WqT, WkT, WvT, WgT, WgkbT, WgkbT + 12 * H_, WoT,
                                           hs, c_hs, flag);

  // 1. fused gkbeta|q|k|v|g projection: BT = [WgkbT;WqT;WkT;WvT;WgT] = [4736][1024];
  //    col tile y=0 runs the gkbeta epilogue (dispatched FIRST -> hidden under grid),
  //    cols [128,4736) routed per 1536-col region into qkraw/vraw/gbuf.
  gemm_bt<<<dim3(M_ / 256, 4736 / 128), 512, 0, stream>>>(c_hs, WgkbT, qkraw, M_, 4736, H_, 3, flag,
                                                          bbf, A_logf, dtf, gkb, betab);

  // 2. all convs (q+k l2norm, v) in one launch: 384 work-threads/row
  conv_all<<<(M_ * 384) / 256, 256, 0, stream>>>(qkraw, vraw, cqf, ckf, cvf, qb, kb, vb);

  // 3. chunked gated delta rule (phase3 fuses rmsnorm + swish gate)
  phase1_kernel<<<NCID, 256, 0, stream>>>(kb, vb, gkb, betab, U0g, Wmg, Gamg);
  phase2_kernel<<<B_ * NHh * 4, 256, 0, stream>>>(kb, U0g, Wmg, Gamg, P0g);
  phase3_kernel<<<NCID, 256, 0, stream>>>(qb, kb, U0g, Wmg, P0g, Gamg, gbuf, gnwf, o_raw);

  // 4. output projection (dtype-flag-selected store)
  gemm_bt<<<dim3(M_ / 256, H_ / 128), 512, 0, stream>>>(o_raw, WoT, d_out, M_, H_, VD, 2, flag,
                                                        nullptr, nullptr, nullptr, nullptr, nullptr);
}

// Round 12
// 398.475 us; speedup vs baseline: 1.0439x; 1.0295x over previous
//
#include <hip/hip_runtime.h>

// ---------- problem constants ----------
#define B_   4
#define L_   2048
#define H_   1024
#define KD   768
#define VD   1536
#define NHh  12
#define DKh  64
#define DVh  128
#define M_   (B_ * L_)   // 8192 rows
#define NC   32          // chunks per sequence (L/64)
#define NCID (B_ * NHh * NC)  // 1536

using bf16x8 = __attribute__((ext_vector_type(8))) __bf16;
using f32x4  = __attribute__((ext_vector_type(4))) float;
using ui4    = __attribute__((ext_vector_type(4))) unsigned int;
using f4v    = __attribute__((ext_vector_type(4))) float;
using u16x4  = __attribute__((ext_vector_type(4))) unsigned short;
using u16x8  = __attribute__((ext_vector_type(8))) unsigned short;

__device__ __forceinline__ float bf2f(unsigned short u) {
  unsigned int x = ((unsigned int)u) << 16;
  return __builtin_bit_cast(float, x);
}
__device__ __forceinline__ unsigned short f2bf(float f) {
  unsigned int u = __builtin_bit_cast(unsigned int, f);
  u += 0x7fffu + ((u >> 16) & 1u);
  return (unsigned short)(u >> 16);
}
__device__ __forceinline__ float sigmoidf_(float x) { return 1.f / (1.f + __expf(-x)); }

// async global->LDS DMA, 16B per lane; lds dest must be wave-uniform base (+lane*16 implicit)
__device__ __forceinline__ void async_copy16(const unsigned short* __restrict__ g,
                                             unsigned short* l) {
  __builtin_amdgcn_global_load_lds((const __attribute__((address_space(1))) unsigned int*)g,
                                   (__attribute__((address_space(3))) unsigned int*)l, 16, 0, 0);
}

// ---------- dtype detector: flag=1 if inputs are fp32, 0 if bf16 ----------
__global__ void detect_dtype(const unsigned short* __restrict__ hs, int* __restrict__ flag) {
  int tid = threadIdx.x;  // 256 threads
  int cnt = 0;
  for (int i = tid; i < 1024; i += 256) {
    int e = (hs[i] >> 7) & 0xFF;
    if (e >= 134) cnt++;
  }
  #pragma unroll
  for (int off = 32; off; off >>= 1) cnt += __shfl_xor(cnt, off);
  __shared__ int red[4];
  if ((tid & 63) == 0) red[tid >> 6] = cnt;
  __syncthreads();
  if (tid == 0) *flag = (red[0] + red[1] + red[2] + red[3] > 100) ? 1 : 0;
}

// ---------- convert 7 small arrays -> canonical fp32 ----------
// conv weights (a=0,1,2) are additionally TRANSPOSED: in [C][4] -> out [4][C]
__global__ void convert_small(const void* s0, const void* s1, const void* s2,
                              const void* s3, const void* s4, const void* s5, const void* s6,
                              float* d0, float* d1, float* d2, float* d3, float* d4,
                              float* d5, float* d6, const int* __restrict__ flag) {
  const int sizes[7] = {KD * 4, KD * 4, VD * 4, NHh, NHh, NHh, DVh};
  int a = blockIdx.y;
  const void* s; float* d;
  switch (a) {
    case 0: s = s0; d = d0; break;  case 1: s = s1; d = d1; break;
    case 2: s = s2; d = d2; break;  case 3: s = s3; d = d3; break;
    case 4: s = s4; d = d4; break;  case 5: s = s5; d = d5; break;
    default: s = s6; d = d6; break;
  }
  int i = blockIdx.x * 256 + threadIdx.x;
  if (i >= sizes[a]) return;
  float v = (*flag) ? ((const float*)s)[i] : bf2f(((const unsigned short*)s)[i]);
  if (a < 3) {
    int C = (a == 2) ? VD : KD;
    d[(i & 3) * C + (i >> 2)] = v;   // transposed [j][c]
  } else {
    d[i] = v;
  }
}

// ---------- ALL weight transposes + hs canonicalization in ONE launch ----------
// blocks [0,6208): 32x32 transpose tiles:
//   Wq 768 | Wk 768 | Wv 1536 | Wg 1536 | Wgk 32 | Wb 32 | Wo 1536
// blocks [6208,14400): hidden_states convert/copy (4 elems x 256 thr each)
__global__ void transpose_all(
    const void* s0, const void* s1, const void* s2, const void* s3,
    const void* s4, const void* s5, const void* s6,
    unsigned short* d0, unsigned short* d1, unsigned short* d2, unsigned short* d3,
    unsigned short* d4, unsigned short* d5, unsigned short* d6,
    const void* __restrict__ hs, unsigned short* __restrict__ c_hs,
    const int* __restrict__ flag) {
  int t = blockIdx.x;
  if (t >= 6208) {
    size_t i = ((size_t)(t - 6208) * 256 + threadIdx.x) * 4;
    if (*flag) {
      f4v v = *(const f4v*)((const float*)hs + i);
      u16x4 o;
      o.x = f2bf(v[0]); o.y = f2bf(v[1]); o.z = f2bf(v[2]); o.w = f2bf(v[3]);
      *(u16x4*)(c_hs + i) = o;
    } else {
      *(u16x4*)(c_hs + i) = *(const u16x4*)((const unsigned short*)hs + i);
    }
    return;
  }
  __shared__ unsigned short tile[32][33];
  const void* in; unsigned short* out; int R, C, ntx, tt;
  if (t < 768)       { in = s0; out = d0; R = 1024; C = 768;  ntx = 24; tt = t; }
  else if (t < 1536) { in = s1; out = d1; R = 1024; C = 768;  ntx = 24; tt = t - 768; }
  else if (t < 3072) { in = s2; out = d2; R = 1024; C = 1536; ntx = 48; tt = t - 1536; }
  else if (t < 4608) { in = s3; out = d3; R = 1024; C = 1536; ntx = 48; tt = t - 3072; }
  else if (t < 4640) { in = s4; out = d4; R = 1024; C = 12;   ntx = 1;  tt = t - 4608; }
  else if (t < 4672) { in = s5; out = d5; R = 1024; C = 12;   ntx = 1;  tt = t - 4640; }
  else               { in = s6; out = d6; R = 1536; C = 1024; ntx = 32; tt = t - 4672; }
  int f = *flag;
  int bx = tt % ntx, by = tt / ntx;
  int c0 = bx * 32, r0 = by * 32;
  int tx = threadIdx.x & 31, ty = threadIdx.x >> 5;
  #pragma unroll
  for (int i = 0; i < 32; i += 8) {
    int r = r0 + ty + i, c = c0 + tx;
    unsigned short v = 0;
    if (r < R && c < C)
      v = f ? f2bf(((const float*)in)[(size_t)r * C + c])
            : ((const unsigned short*)in)[(size_t)r * C + c];
    tile[ty + i][tx] = v;
  }
  __syncthreads();
  #pragma unroll
  for (int i = 0; i < 32; i += 8) {
    int c = c0 + ty + i, r = r0 + tx;
    if (c < C && r < R) out[(size_t)c * R + r] = tile[tx][ty + i];
  }
}

// ---------- MFMA GEMM A: 256x128 tile, BK=32 (for the K=1024 fused proj) ----------
// R11-verified: 512 thr (4x2 waves, acc[4][4]), 48KB dbuf LDS -> 2 blocks/CU,
// counted vmcnt(3), conflict-free swizzle slot = lq ^ ((row>>1)&3) (both sides).
// Best measured for K=1024 (intensity win: B-panel re-reads halved).
// f32mode: 0=bf16, 1=f32, 2=flag-selected,
//          3=fused gkbeta|q|k|v|g routing over N=4736 (gk tile FIRST at y=0).
#define BMt 256
#define BNt 128
#define BKt 32

__global__ __launch_bounds__(512, 4) void gemm_bt(
    const unsigned short* __restrict__ Ag,
    const unsigned short* __restrict__ BTg,
    void* __restrict__ Cg,
    int M, int N, int K, int f32mode, const int* __restrict__ flag,
    const float* __restrict__ bbf, const float* __restrict__ A_logf,
    const float* __restrict__ dtf,
    float* __restrict__ gkb, float* __restrict__ betab) {
  __shared__ __align__(16) unsigned short As[2][BMt * BKt];   // 2 x 16KB
  __shared__ __align__(16) unsigned short Bs[2][BNt * BKt];   // 2 x 8KB
  const int tid = threadIdx.x;
  const int wave = tid >> 6, lane = tid & 63;
  const int wr = wave >> 1, wc = wave & 1;   // 4 x 2 wave grid: 64-row x 64-col per wave
  const int lrow = lane & 15, lq = lane >> 4;
  const int row0 = blockIdx.x * BMt;
  const int bcol0 = blockIdx.y * BNt;
  const bool gkregion = (f32mode == 3) && (bcol0 < BNt);
  // C routing
  unsigned short* Cb = (unsigned short*)Cg;
  int col0 = bcol0, Nst = N;
  if (f32mode == 3 && !gkregion) {
    int r3 = bcol0 - BNt;
    int region = r3 / 1536;
    Cb += (size_t)region * (size_t)M_ * 1536;
    col0 = r3 - region * 1536;
    Nst = 1536;
  }
  f32x4 acc[4][4] = {};
  // staging (per K-tile): A = 1024 16B-chunks (2/thread), B = 512 (1/thread).
  // chunk c: row r = c>>2, LDS slot u = c&3 holds global slot u^((r>>1)&3).
  auto stage = [&](int sb, int k0) {
    #pragma unroll
    for (int i = 0; i < 2; i++) {
      int c = i * 512 + tid;
      int r = c >> 2;
      int kk = ((c & 3) ^ ((r >> 1) & 3)) << 3;   // pre-swizzled source slot
      async_copy16(&Ag[(size_t)(row0 + r) * K + k0 + kk],
                   &As[sb][(i * 512 + wave * 64) * 8]);
    }
    {
      int c = tid;
      int r = c >> 2;
      int kk = ((c & 3) ^ ((r >> 1) & 3)) << 3;
      async_copy16(&BTg[(size_t)(bcol0 + r) * K + k0 + kk],
                   &Bs[sb][(wave * 64) * 8]);
    }
  };
  const int NT = K / BKt;
  stage(0, 0);
  stage(1, BKt);
  for (int t = 0; t < NT; t++) {
    // Drain only tile t's 3 loads (per-wave oldest); tile t+1's stay in flight.
    if (t + 1 < NT) asm volatile("s_waitcnt vmcnt(3)" ::: "memory");
    else            asm volatile("s_waitcnt vmcnt(0)" ::: "memory");
    __builtin_amdgcn_s_barrier();       // all waves' tile-t loads are in LDS
    const int cur = t & 1;
    {
      bf16x8 af[4], bfr[4];
      #pragma unroll
      for (int i = 0; i < 4; i++) {
        int ra = wr * 64 + i * 16 + lrow;
        int sa = lq ^ ((ra >> 1) & 3);
        af[i] = *(const bf16x8*)&As[cur][ra * BKt + (sa << 3)];
        int rb = wc * 64 + i * 16 + lrow;
        int sb2 = lq ^ ((rb >> 1) & 3);
        bfr[i] = *(const bf16x8*)&Bs[cur][rb * BKt + (sb2 << 3)];
      }
      __builtin_amdgcn_s_setprio(1);
      #pragma unroll
      for (int mi = 0; mi < 4; mi++)
        #pragma unroll
        for (int ni = 0; ni < 4; ni++)
          acc[mi][ni] = __builtin_amdgcn_mfma_f32_16x16x32_bf16(af[mi], bfr[ni], acc[mi][ni], 0, 0, 0);
      __builtin_amdgcn_s_setprio(0);
    }
    __builtin_amdgcn_s_barrier();       // all waves done reading buffer cur
    if (t + 2 < NT) stage(cur, (t + 2) * BKt);   // buffer released by barrier
  }
  if (gkregion) {
    // gkbeta epilogue: cols 0..11 gk, 12..23 beta, rest discarded.
    #pragma unroll
    for (int mi = 0; mi < 4; mi++)
      #pragma unroll
      for (int ni = 0; ni < 4; ni++)
        #pragma unroll
        for (int r = 0; r < 4; r++) {
          int rr = row0 + wr * 64 + mi * 16 + lq * 4 + r;
          int cc = wc * 64 + ni * 16 + lrow;
          float v = acc[mi][ni][r];
          if (cc < 12) {
            float tt = v + dtf[cc];
            float sp = (tt > 20.f) ? tt : log1pf(__expf(tt));
            gkb[(size_t)rr * NHh + cc] = -__expf(A_logf[cc]) * sp;
          } else if (cc < 24) {
            betab[(size_t)rr * NHh + (cc - 12)] = sigmoidf_(v + bbf[cc - 12]);
          }
        }
    return;
  }
  bool f32 = (f32mode == 1) || (f32mode == 2 && *flag != 0);
  #pragma unroll
  for (int mi = 0; mi < 4; mi++)
    #pragma unroll
    for (int ni = 0; ni < 4; ni++)
      #pragma unroll
      for (int r = 0; r < 4; r++) {
        int rr = row0 + wr * 64 + mi * 16 + lq * 4 + r;
        int cc = col0 + wc * 64 + ni * 16 + lrow;
        float v = acc[mi][ni][r];
        if (f32) ((float*)Cg)[(size_t)rr * N + cc] = v;
        else     Cb[(size_t)rr * Nst + cc] = f2bf(v);
      }
}

// ---------- MFMA GEMM B: 128x128 tile, BK=64 (for the K=1536 out-proj) ----------
// R9-verified: 512 thr (2x4 waves, acc[4][2]), 64KB dbuf LDS -> 2 blocks/CU,
// counted vmcnt(4), conflict-free 8-slot swizzle (c&7)^(r&7). More MFMA per
// barrier (32 vs 16) amortizes the longer K-loop — best measured for K=1536
// (R11 post-mortem: BK=32 regressed the out-proj ~10us via barrier frequency).
__global__ __launch_bounds__(512, 4) void gemm_bt64(
    const unsigned short* __restrict__ Ag,
    const unsigned short* __restrict__ BTg,
    void* __restrict__ Cg,
    int M, int N, int K, int f32mode, const int* __restrict__ flag) {
  constexpr int BM2 = 128, BK2 = 64;
  __shared__ __align__(16) unsigned short As[2][BM2 * BK2];
  __shared__ __align__(16) unsigned short Bs[2][BM2 * BK2];
  const int tid = threadIdx.x;
  const int wave = tid >> 6, lane = tid & 63;
  const int wr = wave >> 2, wc = wave & 3;   // 2 x 4 wave grid: 64-row x 32-col per wave
  const int lrow = lane & 15, lq = lane >> 4;
  const int row0 = blockIdx.x * BM2;
  const int bcol0 = blockIdx.y * BM2;
  f32x4 acc[4][2] = {};
  // staging: chunk c in [0,1024): r=c>>3, LDS slot u=c&7 holds global slot u^(r&7)
  auto stage = [&](int sb, int k0) {
    #pragma unroll
    for (int i = 0; i < 2; i++) {
      int c = i * 512 + tid;
      int r = c >> 3;
      int kk = ((c & 7) ^ (r & 7)) << 3;   // pre-swizzled source slot
      int ldsbase = (i * 512 + wave * 64) * 8;   // wave-uniform elem offset
      async_copy16(&Ag[(size_t)(row0 + r) * K + k0 + kk], &As[sb][ldsbase]);
      async_copy16(&BTg[(size_t)(bcol0 + r) * K + k0 + kk], &Bs[sb][ldsbase]);
    }
  };
  const int NT = K / BK2;
  stage(0, 0);
  if (NT > 1) stage(1, BK2);
  for (int t = 0; t < NT; t++) {
    // Drain only tile t's 4 loads (per-wave oldest); tile t+1's stay in flight.
    if (t + 1 < NT) asm volatile("s_waitcnt vmcnt(4)" ::: "memory");
    else            asm volatile("s_waitcnt vmcnt(0)" ::: "memory");
    __builtin_amdgcn_s_barrier();       // all waves' tile-t loads are in LDS
    const int cur = t & 1;
    #pragma unroll
    for (int ks = 0; ks < BK2; ks += 32) {
      bf16x8 af[4], bfr[2];
      #pragma unroll
      for (int i = 0; i < 4; i++) {
        int ra = wr * 64 + i * 16 + lrow;
        int sa = ((ks >> 3) + lq) ^ (ra & 7);
        af[i]  = *(const bf16x8*)&As[cur][ra * BK2 + (sa << 3)];
      }
      #pragma unroll
      for (int i = 0; i < 2; i++) {
        int rb = wc * 32 + i * 16 + lrow;
        int sb2 = ((ks >> 3) + lq) ^ (rb & 7);
        bfr[i] = *(const bf16x8*)&Bs[cur][rb * BK2 + (sb2 << 3)];
      }
      __builtin_amdgcn_s_setprio(1);
      #pragma unroll
      for (int mi = 0; mi < 4; mi++)
        #pragma unroll
        for (int ni = 0; ni < 2; ni++)
          acc[mi][ni] = __builtin_amdgcn_mfma_f32_16x16x32_bf16(af[mi], bfr[ni], acc[mi][ni], 0, 0, 0);
      __builtin_amdgcn_s_setprio(0);
    }
    __builtin_amdgcn_s_barrier();       // all waves done reading buffer cur
    if (t + 2 < NT) stage(cur, (t + 2) * BK2);   // buffer released by barrier
  }
  bool f32 = (f32mode == 1) || (f32mode == 2 && *flag != 0);
  #pragma unroll
  for (int mi = 0; mi < 4; mi++)
    #pragma unroll
    for (int ni = 0; ni < 2; ni++)
      #pragma unroll
      for (int r = 0; r < 4; r++) {
        int rr = row0 + wr * 64 + mi * 16 + lq * 4 + r;
        int cc = bcol0 + wc * 32 + ni * 16 + lrow;
        float v = acc[mi][ni][r];
        if (f32) ((float*)Cg)[(size_t)rr * N + cc] = v;
        else     ((unsigned short*)Cg)[(size_t)rr * N + cc] = f2bf(v);
      }
}

// ---------- ALL causal dwconvs in ONE launch ----------
// Per row: 384 work-threads = 96 q (8ch, l2norm) + 96 k (8ch, l2norm) + 192 v (8ch).
__global__ void conv_all(const unsigned short* __restrict__ qkraw,
                         const unsigned short* __restrict__ vraw,
                         const float* __restrict__ cqf, const float* __restrict__ ckf,
                         const float* __restrict__ cvf,
                         unsigned short* __restrict__ qb, unsigned short* __restrict__ kb,
                         unsigned short* __restrict__ vb) {
  int idx = blockIdx.x * 256 + threadIdx.x;
  int row = idx / 384, w = idx - row * 384;
  int l = row & (L_ - 1);
  if (w < 192) {
    int isk = (w >= 96) ? 1 : 0;
    int c = (w - isk * 96) * 8;
    const float* wt = isk ? ckf : cqf;
    const unsigned short* base = qkraw + (size_t)row * 1536 + isk * KD + c;
    float acc[8] = {};
    #pragma unroll
    for (int j = 0; j < 4; j++) {
      int ll = l - 3 + j;
      if (ll >= 0) {
        u16x8 v = *(const u16x8*)(base + (ptrdiff_t)(j - 3) * 1536);
        f4v w0 = *(const f4v*)&wt[j * KD + c];
        f4v w1 = *(const f4v*)&wt[j * KD + c + 4];
        #pragma unroll
        for (int e = 0; e < 4; e++) acc[e] += bf2f(v[e]) * w0[e];
        #pragma unroll
        for (int e = 0; e < 4; e++) acc[4 + e] += bf2f(v[4 + e]) * w1[e];
      }
    }
    float x[8], ss = 0.f;
    #pragma unroll
    for (int e = 0; e < 8; e++) {
      float a = acc[e];
      x[e] = a * sigmoidf_(a);
      ss += x[e] * x[e];
    }
    #pragma unroll
    for (int off = 1; off <= 4; off <<= 1) ss += __shfl_xor(ss, off);
    float inv = 1.f / fmaxf(sqrtf(ss), 1e-12f);
    u16x8 o;
    #pragma unroll
    for (int e = 0; e < 8; e++) o[e] = f2bf(x[e] * inv);
    unsigned short* dst = (isk ? kb : qb) + (size_t)row * KD + c;
    *(u16x8*)dst = o;
  } else {
    int c = (w - 192) * 8;
    const unsigned short* base = vraw + (size_t)row * VD + c;
    float acc[8] = {};
    #pragma unroll
    for (int j = 0; j < 4; j++) {
      int ll = l - 3 + j;
      if (ll >= 0) {
        u16x8 v = *(const u16x8*)(base + (ptrdiff_t)(j - 3) * VD);
        f4v w0 = *(const f4v*)&cvf[j * VD + c];
        f4v w1 = *(const f4v*)&cvf[j * VD + c + 4];
        #pragma unroll
        for (int e = 0; e < 4; e++) acc[e] += bf2f(v[e]) * w0[e];
        #pragma unroll
        for (int e = 0; e < 4; e++) acc[4 + e] += bf2f(v[4 + e]) * w1[e];
      }
    }
    u16x8 o;
    #pragma unroll
    for (int e = 0; e < 8; e++) {
      float a = acc[e];
      o[e] = f2bf(a * sigmoidf_(a));
    }
    *(u16x8*)&vb[(size_t)row * VD + c] = o;
  }
}

// ================= CHUNKED GATED DELTA RULE =================
// ---------- Phase 1: per-chunk precompute (parallel, 1536 blocks) ----------
__global__ __launch_bounds__(256) void phase1_kernel(
    const unsigned short* __restrict__ kb, const unsigned short* __restrict__ vb,
    const float* __restrict__ gkb, const float* __restrict__ betab,
    unsigned short* __restrict__ U0g, unsigned short* __restrict__ Wmg,
    float* __restrict__ Gamg) {
  int cid = blockIdx.x;
  int c = cid & (NC - 1), bh = cid >> 5;
  int h = bh % NHh, b = bh / NHh;
  int bl0 = b * L_ + (c << 6);
  __shared__ __align__(16) unsigned short K_lds[64][72];
  __shared__ __align__(16) unsigned short Ab[64][72];
  __shared__ __align__(16) unsigned short Tb[64][72];
  __shared__ __align__(16) unsigned short TbT[64][72];
  __shared__ __align__(16) unsigned short Qt[64][40];
  __shared__ __align__(16) unsigned short Mpad[16][40];
  __shared__ __align__(16) unsigned short RHSt[192][72];
  __shared__ float G_lds[64], beta_lds[64], besc_lds[64];
  int tid = threadIdx.x;
  int wave = tid >> 6, lane = tid & 63, lq = lane >> 4, lrow = lane & 15;
  {
    u16x4 z = {};
    unsigned short* tb = &Tb[0][0];  unsigned short* tt = &TbT[0][0];
    for (int i = tid * 4; i < 64 * 72; i += 1024) {
      *(u16x4*)&tb[i] = z;  *(u16x4*)&tt[i] = z;
    }
    unsigned short* qt = &Qt[0][0];
    for (int i = tid * 4; i < 64 * 40; i += 1024) *(u16x4*)&qt[i] = z;
    if (tid < 160) *(u16x4*)&(&Mpad[0][0])[tid * 4] = z;
  }
  {
    int j = tid >> 2, d0 = (tid & 3) << 4;
    const ui4* src = (const ui4*)&kb[(size_t)(bl0 + j) * KD + h * 64 + d0];
    *(ui4*)&K_lds[j][d0]     = src[0];
    *(ui4*)&K_lds[j][d0 + 8] = src[1];
  }
  if (tid < 64) {
    float g  = gkb[(size_t)(bl0 + tid) * NHh + h];
    float bt = betab[(size_t)(bl0 + tid) * NHh + h];
    #pragma unroll
    for (int off = 1; off < 64; off <<= 1) {
      int src = lane - off;
      float y = __shfl(g, src < 0 ? 0 : src);
      if (lane >= off) g += y;
    }
    G_lds[tid]    = g;
    beta_lds[tid] = bt;
    besc_lds[tid] = bt * __expf(g);
    Gamg[(size_t)cid * 64 + tid] = g;
  }
  __syncthreads();
  #pragma unroll
  for (int mt = 0; mt < 4; mt++) {
    f32x4 acc = {};
    #pragma unroll
    for (int ks = 0; ks < 2; ks++) {
      bf16x8 a  = *(const bf16x8*)&K_lds[wave * 16 + lrow][ks * 32 + lq * 8];
      bf16x8 b2 = *(const bf16x8*)&K_lds[mt * 16 + lrow][ks * 32 + lq * 8];
      acc = __builtin_amdgcn_mfma_f32_16x16x32_bf16(a, b2, acc, 0, 0, 0);
    }
    #pragma unroll
    for (int r = 0; r < 4; r++) {
      int j = wave * 16 + lq * 4 + r, m = mt * 16 + lrow;
      Ab[j][m] = (m < j) ? f2bf(beta_lds[j] * __expf(G_lds[j] - G_lds[m]) * acc[r])
                         : (unsigned short)0;
    }
  }
  __syncthreads();
  if (wave == 0) {
    int blk = lq, cc = lrow, base = blk * 16;
    float t[16];
    t[0] = (cc == 0) ? 1.f : 0.f;
    #pragma unroll
    for (int j = 1; j < 16; j++) {
      float s = 0.f;
      #pragma unroll
      for (int m = 0; m < j; m++)
        s += bf2f(Ab[base + j][base + m]) * t[m];
      t[j] = ((cc == j) ? 1.f : 0.f) - s;
    }
    #pragma unroll
    for (int j = 0; j < 16; j++) {
      unsigned short bv = f2bf(t[j]);
      Tb[base + j][base + cc]  = bv;
      TbT[base + cc][base + j] = bv;
    }
  } else {
    int r = tid - 64;   // 0..191
    if (r < 128) {
      const unsigned short* vp = &vb[(size_t)bl0 * VD + h * 128 + r];
      for (int j = 0; j < 64; j++)
        RHSt[r][j] = f2bf(beta_lds[j] * bf2f(vp[(size_t)j * VD]));
    } else {
      int d = r - 128;
      for (int j = 0; j < 64; j++)
        RHSt[r][j] = f2bf(besc_lds[j] * bf2f(K_lds[j][d]));
    }
  }
  __syncthreads();
  #pragma unroll
  for (int lvl = 1; lvl < 4; lvl++) {
    {
      int m = tid >> 4, k = tid & 15;
      Ab[lvl * 16 + m][lvl * 16 + k] = 0;
      Mpad[m][k] = Tb[lvl * 16 + m][lvl * 16 + k];
    }
    __syncthreads();
    f32x4 accP = {};
    #pragma unroll
    for (int ks2 = 0; ks2 < 2; ks2++) {
      bf16x8 a  = *(const bf16x8*)&Ab[lvl * 16 + lrow][ks2 * 32 + lq * 8];
      bf16x8 b2 = *(const bf16x8*)&TbT[wave * 16 + lrow][ks2 * 32 + lq * 8];
      accP = __builtin_amdgcn_mfma_f32_16x16x32_bf16(a, b2, accP, 0, 0, 0);
    }
    {
      int col = wave * 16 + lrow;
      u16x4 qp;
      #pragma unroll
      for (int r = 0; r < 4; r++) {
        int krow = lq * 4 + r;
        float e = (col == lvl * 16 + krow) ? 1.f : 0.f;
        ((unsigned short*)&qp)[r] = f2bf(e - accP[r]);
      }
      *(u16x4*)&Qt[col][lq * 4] = qp;
    }
    __syncthreads();
    {
      bf16x8 am = *(const bf16x8*)&Mpad[lrow][lq * 8];
      bf16x8 bq = *(const bf16x8*)&Qt[wave * 16 + lrow][lq * 8];
      f32x4 accR = {};
      accR = __builtin_amdgcn_mfma_f32_16x16x32_bf16(am, bq, accR, 0, 0, 0);
      #pragma unroll
      for (int r = 0; r < 4; r++) {
        int row = lvl * 16 + lq * 4 + r, col = wave * 16 + lrow;
        unsigned short bv = f2bf(accR[r]);
        Tb[row][col]  = bv;
        TbT[col][row] = bv;
      }
    }
    __syncthreads();
  }
  bf16x8 af0 = *(const bf16x8*)&Tb[wave * 16 + lrow][lq * 8];
  bf16x8 af1 = *(const bf16x8*)&Tb[wave * 16 + lrow][32 + lq * 8];
  #pragma unroll
  for (int nt = 0; nt < 12; nt++) {
    f32x4 acc = {};
    bf16x8 b0 = *(const bf16x8*)&RHSt[nt * 16 + lrow][lq * 8];
    bf16x8 b1 = *(const bf16x8*)&RHSt[nt * 16 + lrow][32 + lq * 8];
    acc = __builtin_amdgcn_mfma_f32_16x16x32_bf16(af0, b0, acc, 0, 0, 0);
    acc = __builtin_amdgcn_mfma_f32_16x16x32_bf16(af1, b1, acc, 0, 0, 0);
    #pragma unroll
    for (int r = 0; r < 4; r++) {
      int i = wave * 16 + lq * 4 + r;
      int col = nt * 16 + lrow;
      if (nt < 8) U0g[(size_t)cid * 8192 + i * 128 + col] = f2bf(acc[r]);
      else        Wmg[(size_t)cid * 4096 + i * 64 + (col - 128)] = f2bf(acc[r]);
    }
  }
}

// ---------- Phase 2: inter-chunk state recurrence, v-split (192 blocks) ----------
__global__ __launch_bounds__(256) void phase2_kernel(
    const unsigned short* __restrict__ kb,
    const unsigned short* __restrict__ U0g, const unsigned short* __restrict__ Wmg,
    const float* __restrict__ Gamg, unsigned short* __restrict__ P0g) {
  int blk = blockIdx.x;              // bh*4 + vc
  int vc = blk & 3, bh = blk >> 2;
  int h = bh % NHh, b = bh / NHh;
  __shared__ __align__(16) unsigned short P_bf[32][72];    // S0 slice [v][d]
  __shared__ __align__(16) unsigned short Wm_lds[64][72];  // [j][d]
  __shared__ __align__(16) unsigned short Ktmp[64][72];    // [j][d]
  __shared__ __align__(16) unsigned short KpT_lds[64][72]; // [d][j]
  __shared__ __align__(16) unsigned short U0_lds[64][40];  // [j][v32]
  __shared__ __align__(16) unsigned short UT_lds[32][72];  // [v][j]
  __shared__ float G2[64];
  int tid = threadIdx.x;
  int wave = tid >> 6, lane = tid & 63, lq = lane >> 4, lrow = lane & 15;
  int vt = wave & 1, dbase = (wave >> 1) * 2;
  f32x4 P[2] = {};
  int pj = tid >> 2, px = (tid & 3) << 4;   // Wm/K: 32B per thread
  int pv = (tid & 3) << 3;                  // U0: 16B per thread (8 shorts)
  ui4 pf_wm0, pf_wm1, pf_k0, pf_k1, pf_u0;
  float pf_g = 0.f;
  {
    size_t cid0 = (size_t)bh * NC;
    int bl0 = b * L_;
    pf_wm0 = *(const ui4*)&Wmg[cid0 * 4096 + pj * 64 + px];
    pf_wm1 = *(const ui4*)&Wmg[cid0 * 4096 + pj * 64 + px + 8];
    pf_k0  = *(const ui4*)&kb[(size_t)(bl0 + pj) * KD + h * 64 + px];
    pf_k1  = *(const ui4*)&kb[(size_t)(bl0 + pj) * KD + h * 64 + px + 8];
    pf_u0  = *(const ui4*)&U0g[cid0 * 8192 + pj * 128 + vc * 32 + pv];
    if (tid < 64) pf_g = Gamg[cid0 * 64 + tid];
  }
  for (int c = 0; c < NC; c++) {
    size_t cid = (size_t)bh * NC + c;
    #pragma unroll
    for (int di = 0; di < 2; di++)
      #pragma unroll
      for (int r = 0; r < 4; r++)
        P_bf[vt * 16 + lq * 4 + r][(dbase + di) * 16 + lrow] = f2bf(P[di][r]);
    *(ui4*)&Wm_lds[pj][px]     = pf_wm0;
    *(ui4*)&Wm_lds[pj][px + 8] = pf_wm1;
    *(ui4*)&Ktmp[pj][px]       = pf_k0;
    *(ui4*)&Ktmp[pj][px + 8]   = pf_k1;
    *(ui4*)&U0_lds[pj][pv]     = pf_u0;
    if (tid < 64) G2[tid] = pf_g;
    __syncthreads();
    float gend = __expf(G2[63]);
    {
      int v = tid >> 3, d8 = (tid & 7) << 3;
      *(ui4*)&P0g[cid * 8192 + (size_t)(vc * 32 + v) * 64 + d8] = *(const ui4*)&P_bf[v][d8];
    }
    if (c + 1 < NC) {
      size_t cid1 = cid + 1;
      int bl1 = b * L_ + ((c + 1) << 6);
      pf_wm0 = *(const ui4*)&Wmg[cid1 * 4096 + pj * 64 + px];
      pf_wm1 = *(const ui4*)&Wmg[cid1 * 4096 + pj * 64 + px + 8];
      pf_k0  = *(const ui4*)&kb[(size_t)(bl1 + pj) * KD + h * 64 + px];
      pf_k1  = *(const ui4*)&kb[(size_t)(bl1 + pj) * KD + h * 64 + px + 8];
      pf_u0  = *(const ui4*)&U0g[cid1 * 8192 + pj * 128 + vc * 32 + pv];
      if (tid < 64) pf_g = Gamg[cid1 * 64 + tid];
    }
    {
      int d = tid & 63, j0 = (tid >> 6) << 4;
      float Ge = G2[63];
      #pragma unroll
      for (int i = 0; i < 16; i++) {
        int j = j0 + i;
        KpT_lds[d][j] = f2bf(__expf(Ge - G2[j]) * bf2f(Ktmp[j][d]));
      }
    }
    #pragma unroll
    for (int vt2 = 0; vt2 < 2; vt2++) {
      f32x4 acc = {};
      #pragma unroll
      for (int ks2 = 0; ks2 < 2; ks2++) {
        bf16x8 a  = *(const bf16x8*)&Wm_lds[wave * 16 + lrow][ks2 * 32 + lq * 8];
        bf16x8 b2 = *(const bf16x8*)&P_bf[vt2 * 16 + lrow][ks2 * 32 + lq * 8];
        acc = __builtin_amdgcn_mfma_f32_16x16x32_bf16(a, b2, acc, 0, 0, 0);
      }
      u16x4 p;
      #pragma unroll
      for (int r = 0; r < 4; r++) {
        int j = wave * 16 + lq * 4 + r;
        ((unsigned short*)&p)[r] = f2bf(bf2f(U0_lds[j][vt2 * 16 + lrow]) - acc[r]);
      }
      *(u16x4*)&UT_lds[vt2 * 16 + lrow][wave * 16 + lq * 4] = p;
    }
    __syncthreads();
    #pragma unroll
    for (int di = 0; di < 2; di++) {
      f32x4 acc = P[di];
      #pragma unroll
      for (int r = 0; r < 4; r++) acc[r] *= gend;
      #pragma unroll
      for (int ks2 = 0; ks2 < 2; ks2++) {
        bf16x8 a  = *(const bf16x8*)&UT_lds[vt * 16 + lrow][ks2 * 32 + lq * 8];
        bf16x8 b2 = *(const bf16x8*)&KpT_lds[(dbase + di) * 16 + lrow][ks2 * 32 + lq * 8];
        acc = __builtin_amdgcn_mfma_f32_16x16x32_bf16(a, b2, acc, 0, 0, 0);
      }
      P[di] = acc;
    }
  }
}

// ---------- Phase 3: per-chunk output + FUSED rmsnorm/gate (1536 blocks) ----------
__global__ __launch_bounds__(256) void phase3_kernel(
    const unsigned short* __restrict__ qb, const unsigned short* __restrict__ kb,
    const unsigned short* __restrict__ U0g, const unsigned short* __restrict__ Wmg,
    const unsigned short* __restrict__ P0g, const float* __restrict__ Gamg,
    const unsigned short* __restrict__ gb, const float* __restrict__ gnw,
    unsigned short* __restrict__ o_raw) {
  int cid = blockIdx.x;
  int c = cid & (NC - 1), bh = cid >> 5;
  int h = bh % NHh, b = bh / NHh;
  int bl0 = b * L_ + (c << 6);
  __shared__ __align__(16) unsigned short Q_lds[64][72];
  __shared__ __align__(16) unsigned short K_lds[64][72];
  __shared__ __align__(16) unsigned short WM_lds[64][72];
  __shared__ __align__(16) unsigned short P0_lds[128][72];
  __shared__ __align__(16) unsigned short U0_lds[64][128];
  __shared__ __align__(16) unsigned short UT_lds[128][72];
  __shared__ float G_lds[64];
  int tid = threadIdx.x;
  int wave = tid >> 6, lane = tid & 63, lq = lane >> 4, lrow = lane & 15;
  // early g prefetch (consumed after UT build; hides HBM latency under MFMAs)
  ui4 gpre[4];
  float gnww[8];
  {
    int j = tid >> 2, c0 = (tid & 3) << 5;
    const ui4* gs = (const ui4*)&gb[(size_t)(bl0 + j) * VD + h * 128 + c0];
    gpre[0] = gs[0]; gpre[1] = gs[1]; gpre[2] = gs[2]; gpre[3] = gs[3];
    #pragma unroll
    for (int nt = 0; nt < 8; nt++) gnww[nt] = gnw[nt * 16 + lrow];
  }
  {
    int j = tid >> 2, d0 = (tid & 3) << 4;
    const ui4* qs = (const ui4*)&qb[(size_t)(bl0 + j) * KD + h * 64 + d0];
    *(ui4*)&Q_lds[j][d0] = qs[0];  *(ui4*)&Q_lds[j][d0 + 8] = qs[1];
    const ui4* ks = (const ui4*)&kb[(size_t)(bl0 + j) * KD + h * 64 + d0];
    *(ui4*)&K_lds[j][d0] = ks[0];  *(ui4*)&K_lds[j][d0 + 8] = ks[1];
    const ui4* ws = (const ui4*)&Wmg[(size_t)cid * 4096 + j * 64 + d0];
    *(ui4*)&WM_lds[j][d0] = ws[0]; *(ui4*)&WM_lds[j][d0 + 8] = ws[1];
    int v = tid >> 1, e0 = (tid & 1) << 5;
    const ui4* ps = (const ui4*)&P0g[(size_t)cid * 8192 + v * 64 + e0];
    *(ui4*)&P0_lds[v][e0]      = ps[0]; *(ui4*)&P0_lds[v][e0 + 8]  = ps[1];
    *(ui4*)&P0_lds[v][e0 + 16] = ps[2]; *(ui4*)&P0_lds[v][e0 + 24] = ps[3];
    int e1 = tid * 32;
    const ui4* us = (const ui4*)&U0g[(size_t)cid * 8192 + e1];
    ui4* ud = (ui4*)&U0_lds[0][e1];
    ud[0] = us[0]; ud[1] = us[1]; ud[2] = us[2]; ud[3] = us[3];
    if (tid < 64) G_lds[tid] = Gamg[(size_t)cid * 64 + tid];
  }
  __syncthreads();
  #pragma unroll
  for (int nt = 0; nt < 8; nt++) {
    f32x4 acc = {};
    #pragma unroll
    for (int ks2 = 0; ks2 < 2; ks2++) {
      bf16x8 a  = *(const bf16x8*)&WM_lds[wave * 16 + lrow][ks2 * 32 + lq * 8];
      bf16x8 b2 = *(const bf16x8*)&P0_lds[nt * 16 + lrow][ks2 * 32 + lq * 8];
      acc = __builtin_amdgcn_mfma_f32_16x16x32_bf16(a, b2, acc, 0, 0, 0);
    }
    u16x4 p;
    #pragma unroll
    for (int r = 0; r < 4; r++) {
      int j = wave * 16 + lq * 4 + r;
      ((unsigned short*)&p)[r] = f2bf(bf2f(U0_lds[j][nt * 16 + lrow]) - acc[r]);
    }
    *(u16x4*)&UT_lds[nt * 16 + lrow][wave * 16 + lq * 4] = p;
  }
  __syncthreads();
  // U0_lds is dead now -> park g there (reads happen after the next barrier)
  {
    int j = tid >> 2, c0 = (tid & 3) << 5;
    ui4* gd = (ui4*)&U0_lds[j][c0];
    gd[0] = gpre[0]; gd[1] = gpre[1]; gd[2] = gpre[2]; gd[3] = gpre[3];
  }
  #pragma unroll
  for (int mt = 0; mt < 4; mt++) {
    f32x4 acc = {};
    #pragma unroll
    for (int ks2 = 0; ks2 < 2; ks2++) {
      bf16x8 a  = *(const bf16x8*)&Q_lds[wave * 16 + lrow][ks2 * 32 + lq * 8];
      bf16x8 b2 = *(const bf16x8*)&K_lds[mt * 16 + lrow][ks2 * 32 + lq * 8];
      acc = __builtin_amdgcn_mfma_f32_16x16x32_bf16(a, b2, acc, 0, 0, 0);
    }
    #pragma unroll
    for (int r = 0; r < 4; r++) {
      int i = wave * 16 + lq * 4 + r, j = mt * 16 + lrow;
      WM_lds[i][j] = (j <= i) ? f2bf(__expf(G_lds[i] - G_lds[j]) * acc[r]) : (unsigned short)0;
    }
  }
  __syncthreads();
  float ov[8][4];
  float eg[4];
  #pragma unroll
  for (int r = 0; r < 4; r++) eg[r] = __expf(G_lds[wave * 16 + lq * 4 + r]);
  #pragma unroll
  for (int nt = 0; nt < 8; nt++) {
    f32x4 accO = {}, accS = {};
    #pragma unroll
    for (int ks2 = 0; ks2 < 2; ks2++) {
      bf16x8 aM = *(const bf16x8*)&WM_lds[wave * 16 + lrow][ks2 * 32 + lq * 8];
      bf16x8 bU = *(const bf16x8*)&UT_lds[nt * 16 + lrow][ks2 * 32 + lq * 8];
      accO = __builtin_amdgcn_mfma_f32_16x16x32_bf16(aM, bU, accO, 0, 0, 0);
      bf16x8 aQ = *(const bf16x8*)&Q_lds[wave * 16 + lrow][ks2 * 32 + lq * 8];
      bf16x8 bP = *(const bf16x8*)&P0_lds[nt * 16 + lrow][ks2 * 32 + lq * 8];
      accS = __builtin_amdgcn_mfma_f32_16x16x32_bf16(aQ, bP, accS, 0, 0, 0);
    }
    #pragma unroll
    for (int r = 0; r < 4; r++) ov[nt][r] = accO[r] + eg[r] * accS[r];
  }
  // fused rmsnorm + gnorm_w * silu(g): per-row reduce over 128 cols
  float inv_[4];
  #pragma unroll
  for (int r = 0; r < 4; r++) {
    float ss = 0.f;
    #pragma unroll
    for (int nt = 0; nt < 8; nt++) ss += ov[nt][r] * ov[nt][r];
    #pragma unroll
    for (int off2 = 1; off2 <= 8; off2 <<= 1) ss += __shfl_xor(ss, off2);
    inv_[r] = rsqrtf(ss * (1.f / 128.f) + 1e-5f);
  }
  #pragma unroll
  for (int nt = 0; nt < 8; nt++) {
    #pragma unroll
    for (int r = 0; r < 4; r++) {
      int i = wave * 16 + lq * 4 + r;
      float gv = bf2f(U0_lds[i][nt * 16 + lrow]);
      float o = ov[nt][r] * inv_[r] * gnww[nt] * (gv * sigmoidf_(gv));
      o_raw[(size_t)(bl0 + i) * VD + h * 128 + nt * 16 + lrow] = f2bf(o);
    }
  }
}

// ---------- host launch ----------
extern "C" void kernel_launch(void* const* d_in, const int* in_sizes, int n_in,
                              void* d_out, int out_size, void* d_ws, size_t ws_size,
                              hipStream_t stream) {
  const void* hs      = d_in[0];
  const void* Wq      = d_in[1];
  const void* Wk      = d_in[2];
  const void* Wv      = d_in[3];
  const void* Wg      = d_in[4];
  const void* Wgk     = d_in[5];
  const void* Wb      = d_in[6];
  const void* bb      = d_in[7];
  const void* cq      = d_in[8];
  const void* ck      = d_in[9];
  const void* cv      = d_in[10];
  const void* A_log   = d_in[11];
  const void* gnorm_w = d_in[12];
  const void* Wo      = d_in[13];
  const void* dt_bias = d_in[14];

  char* wsB = (char*)d_ws;
  size_t off = 0;
  auto walloc = [&](size_t bytes) -> char* {
    char* p = wsB + off;
    off += (bytes + 1023) & ~(size_t)1023;
    return p;
  };
  int* flag = (int*)walloc(1024);
  // NOTE: WgkbT..WqT..WgT must stay contiguous (fused BT of [4736][1024], gk
  // region FIRST); all sizes are multiples of 1024 so walloc adds no padding.
  unsigned short* WgkbT = (unsigned short*)walloc((size_t)128 * H_ * 2);
  unsigned short* WqT   = (unsigned short*)walloc((size_t)KD * H_ * 2);
  unsigned short* WkT   = (unsigned short*)walloc((size_t)KD * H_ * 2);
  unsigned short* WvT   = (unsigned short*)walloc((size_t)VD * H_ * 2);
  unsigned short* WgT   = (unsigned short*)walloc((size_t)VD * H_ * 2);
  unsigned short* WoT   = (unsigned short*)walloc((size_t)H_ * VD * 2);
  float* cqf   = (float*)walloc((size_t)KD * 4 * 4);
  float* ckf   = (float*)walloc((size_t)KD * 4 * 4);
  float* cvf   = (float*)walloc((size_t)VD * 4 * 4);
  float* bbf   = (float*)walloc(NHh * 4);
  float* A_logf= (float*)walloc(NHh * 4);
  float* dtf   = (float*)walloc(NHh * 4);
  float* gnwf  = (float*)walloc(DVh * 4);
  float* gkb   = (float*)walloc((size_t)M_ * NHh * 4);
  float* betab = (float*)walloc((size_t)M_ * NHh * 4);
  float* Gamg  = (float*)walloc((size_t)NCID * 64 * 4);
  unsigned short* c_hs  = (unsigned short*)walloc((size_t)M_ * H_ * 2);
  // qkraw/vraw/gbuf must stay contiguous (fused GEMM C routing).
  unsigned short* qkraw = (unsigned short*)walloc((size_t)M_ * 1536 * 2);
  unsigned short* vraw  = (unsigned short*)walloc((size_t)M_ * VD * 2);
  unsigned short* gbuf  = (unsigned short*)walloc((size_t)M_ * VD * 2);
  unsigned short* qb    = (unsigned short*)walloc((size_t)M_ * KD * 2);
  unsigned short* kb    = (unsigned short*)walloc((size_t)M_ * KD * 2);
  unsigned short* vb    = (unsigned short*)walloc((size_t)M_ * VD * 2);
  // overlays (safe by launch order):
  unsigned short* Wmg   = c_hs;
  unsigned short* U0g   = qkraw;
  unsigned short* o_raw = vraw;
  unsigned short* P0g   = vb;

  // 0. dtype detection + canonicalization (transposes + hs convert in ONE launch)
  detect_dtype<<<1, 256, 0, stream>>>((const unsigned short*)hs, flag);
  convert_small<<<dim3(24, 7), 256, 0, stream>>>(cq, ck, cv, bb, A_log, dt_bias, gnorm_w,
                                                 cqf, ckf, cvf, bbf, A_logf, dtf, gnwf, flag);
  transpose_all<<<14400, 256, 0, stream>>>(Wq, Wk, Wv, Wg, Wgk, Wb, Wo,
                                           WqT, WkT, WvT, WgT, WgkbT, WgkbT + 12 * H_, WoT,
                                           hs, c_hs, flag);

  // 1. fused gkbeta|q|k|v|g projection (256x128/BK=32 kernel — best for K=1024):
  //    BT = [WgkbT;WqT;WkT;WvT;WgT] = [4736][1024]; col tile y=0 runs the gkbeta
  //    epilogue (dispatched FIRST -> hidden under grid), cols [128,4736) routed
  //    per 1536-col region into qkraw/vraw/gbuf.
  gemm_bt<<<dim3(M_ / 256, 4736 / 128), 512, 0, stream>>>(c_hs, WgkbT, qkraw, M_, 4736, H_, 3, flag,
                                                          bbf, A_logf, dtf, gkb, betab);

  // 2. all convs (q+k l2norm, v) in one launch: 384 work-threads/row
  conv_all<<<(M_ * 384) / 256, 256, 0, stream>>>(qkraw, vraw, cqf, ckf, cvf, qb, kb, vb);

  // 3. chunked gated delta rule (phase3 fuses rmsnorm + swish gate)
  phase1_kernel<<<NCID, 256, 0, stream>>>(kb, vb, gkb, betab, U0g, Wmg, Gamg);
  phase2_kernel<<<B_ * NHh * 4, 256, 0, stream>>>(kb, U0g, Wmg, Gamg, P0g);
  phase3_kernel<<<NCID, 256, 0, stream>>>(qb, kb, U0g, Wmg, P0g, Gamg, gbuf, gnwf, o_raw);

  // 4. output projection (128x128/BK=64 kernel — best for K=1536)
  gemm_bt64<<<dim3(M_ / 128, H_ / 128), 512, 0, stream>>>(o_raw, WoT, d_out, M_, H_, VD, 2, flag);
}